// Round 5
// baseline (17867.862 us; speedup 1.0000x reference)
//
#include <hip/hip_runtime.h>
#include <hip/hip_cooperative_groups.h>
#include <math.h>

namespace cg = cooperative_groups;

#define BB 256
#define TT 128
#define NN 512
#define HH 512
#define G3 1536
#define SLAB (HH * BB)     // 131072 elems: one [512][256] / [256][512] slab
#define XSLAB (G3 * BB)    // 393216 floats: one [1536][256] xi slab
#define NBLK 672
#define NTHR 256

typedef __attribute__((ext_vector_type(8))) short bf16x8;   // 8 bf16 = 4 VGPRs
typedef __attribute__((ext_vector_type(4))) float f32x4;

struct PA {
    const float* x;
    const float* Wih0; const float* Whh0; const float* Wih1; const float* Whh1;
    const float* bih0; const float* bhh0; const float* bih1; const float* bhh1;
    unsigned short *W0ih_h, *W0ih_l, *W0hh_h, *W0hh_l;
    unsigned short *W1ih_h, *W1ih_l, *W1hh_h, *W1hh_l;
    unsigned short *Xh, *Xl, *H0h, *H0l, *H1h, *H1l;
    float *xi0, *xi1, *h0f, *h1f;
};

__device__ __forceinline__ unsigned short bf16_rne(float f) {
    union { float f; unsigned int u; } v; v.f = f;
    unsigned int r = (v.u + 0x7fffu + ((v.u >> 16) & 1u)) >> 16;
    return (unsigned short)r;
}
__device__ __forceinline__ float bf16_tof(unsigned short h) {
    union { float f; unsigned int u; } v; v.u = ((unsigned int)h) << 16;
    return v.f;
}
__device__ __forceinline__ float sigm(float v) { return 1.f / (1.f + expf(-v)); }

__device__ __forceinline__ void conv4(const float* src, unsigned short* dh,
                                      unsigned short* dl) {
    float4 v = *(const float4*)src;
    float f[4] = {v.x, v.y, v.z, v.w};
    ushort4 h, l;
    unsigned short* hp = (unsigned short*)&h;
    unsigned short* lp = (unsigned short*)&l;
#pragma unroll
    for (int q = 0; q < 4; ++q) {
        unsigned short hh = bf16_rne(f[q]);
        hp[q] = hh;
        lp[q] = bf16_rne(f[q] - bf16_tof(hh));
    }
    *(ushort4*)dh = h;
    *(ushort4*)dl = l;
}

__global__ void zero_kernel(float* p, int n) {
    int i = blockIdx.x * blockDim.x + threadIdx.x;
    if (i < n) p[i] = 0.f;
}

__global__ __launch_bounds__(256) void convert_split(
    const float* __restrict__ in, unsigned short* __restrict__ hi,
    unsigned short* __restrict__ lo, int n) {
    int i = (blockIdx.x * 256 + threadIdx.x) * 4;
    if (i >= n) return;
    conv4(in + i, hi + i, lo + i);
}

// ---- pipeline sections ----------------------------------------------------

// xi GEMM: out[g][b] = sum_k W[g][k]*Brow[b][k] + bias[g]; tile 64g x 32b
__device__ __forceinline__ void xi_block(int g0, int b0,
    const unsigned short* __restrict__ Wh, const unsigned short* __restrict__ Wl,
    const unsigned short* __restrict__ Bh, const unsigned short* __restrict__ Bl,
    const float* __restrict__ bias, float* __restrict__ out, unsigned char* smem) {
    unsigned short (*As)[64][40] = (unsigned short (*)[64][40])smem;             // 10240 B
    unsigned short (*Bs)[32][40] = (unsigned short (*)[32][40])(smem + 10240);   // 5120 B
    const int tid = threadIdx.x;
    const int lane = tid & 63, w = tid >> 6;
    const int l15 = lane & 15, l4 = lane >> 4;
    f32x4 acc0 = {0, 0, 0, 0}, acc1 = {0, 0, 0, 0};
    for (int kc = 0; kc < 512; kc += 32) {
        uint4 av[2], bv;
#pragma unroll
        for (int i = 0; i < 2; ++i) {
            int idx = tid + 256 * i;
            int half = idx >> 8, rem = idx & 255;
            int row = rem >> 2, quad = rem & 3;
            const unsigned short* srcp = half ? Wl : Wh;
            av[i] = *(const uint4*)(srcp + (size_t)(g0 + row) * 512 + kc + quad * 8);
        }
        {
            int half = tid >> 7, rem = tid & 127;
            int row = rem >> 2, quad = rem & 3;
            const unsigned short* srcp = half ? Bl : Bh;
            bv = *(const uint4*)(srcp + (size_t)(b0 + row) * 512 + kc + quad * 8);
        }
        __syncthreads();
#pragma unroll
        for (int i = 0; i < 2; ++i) {
            int idx = tid + 256 * i;
            int half = idx >> 8, rem = idx & 255;
            int row = rem >> 2, quad = rem & 3;
            *(uint4*)&As[half][row][quad * 8] = av[i];
        }
        {
            int half = tid >> 7, rem = tid & 127;
            int row = rem >> 2, quad = rem & 3;
            *(uint4*)&Bs[half][row][quad * 8] = bv;
        }
        __syncthreads();
        bf16x8 ah = *(const bf16x8*)&As[0][w * 16 + l15][l4 * 8];
        bf16x8 al = *(const bf16x8*)&As[1][w * 16 + l15][l4 * 8];
        bf16x8 bh0 = *(const bf16x8*)&Bs[0][l15][l4 * 8];
        bf16x8 bl0 = *(const bf16x8*)&Bs[1][l15][l4 * 8];
        bf16x8 bh1 = *(const bf16x8*)&Bs[0][16 + l15][l4 * 8];
        bf16x8 bl1 = *(const bf16x8*)&Bs[1][16 + l15][l4 * 8];
        acc0 = __builtin_amdgcn_mfma_f32_16x16x32_bf16(ah, bh0, acc0, 0, 0, 0);
        acc0 = __builtin_amdgcn_mfma_f32_16x16x32_bf16(ah, bl0, acc0, 0, 0, 0);
        acc0 = __builtin_amdgcn_mfma_f32_16x16x32_bf16(al, bh0, acc0, 0, 0, 0);
        acc1 = __builtin_amdgcn_mfma_f32_16x16x32_bf16(ah, bh1, acc1, 0, 0, 0);
        acc1 = __builtin_amdgcn_mfma_f32_16x16x32_bf16(ah, bl1, acc1, 0, 0, 0);
        acc1 = __builtin_amdgcn_mfma_f32_16x16x32_bf16(al, bh1, acc1, 0, 0, 0);
    }
#pragma unroll
    for (int r = 0; r < 4; ++r) {
        int g = g0 + w * 16 + l4 * 4 + r;
        float bvs = bias[g];
        out[(size_t)g * 256 + b0 + l15] = acc0[r] + bvs;
        out[(size_t)g * 256 + b0 + 16 + l15] = acc1[r] + bvs;
    }
}

// recurrent step: gh = h@Whh^T (+bhh), gates, h-update; tile 32j(x3 gates) x 32b
__device__ __forceinline__ void rec_block(int j0, int b0,
    const unsigned short* __restrict__ Wh, const unsigned short* __restrict__ Wl,
    const unsigned short* __restrict__ Hbh, const unsigned short* __restrict__ Hbl,
    const float* __restrict__ xi, const float* __restrict__ bhh,
    const float* __restrict__ hprevf, float* __restrict__ hnewf,
    unsigned short* __restrict__ Hnh, unsigned short* __restrict__ Hnl,
    unsigned char* smem) {
    unsigned short (*As)[96][40] = (unsigned short (*)[96][40])smem;             // 15360 B
    unsigned short (*Bs)[32][40] = (unsigned short (*)[32][40])(smem + 15360);   // 5120 B
    float (*hl)[36] = (float (*)[36])(smem + 20480);                             // 4608 B
    const int tid = threadIdx.x;
    const int lane = tid & 63, w = tid >> 6;
    const int l15 = lane & 15, l4 = lane >> 4;
    const int jf = w >> 1, bf = w & 1;
    f32x4 aR = {0, 0, 0, 0}, aZ = aR, aN = aR;
    for (int kc = 0; kc < 512; kc += 32) {
        uint4 av[3], bv;
#pragma unroll
        for (int i = 0; i < 3; ++i) {
            int idx = tid + 256 * i;                 // 0..767
            int half = idx >= 384;
            int rem = half ? idx - 384 : idx;
            int row = rem >> 2, quad = rem & 3;      // row 0..95
            int gate = row >> 5, rl = row & 31;
            const unsigned short* srcp = half ? Wl : Wh;
            av[i] = *(const uint4*)(srcp + (size_t)(gate * 512 + j0 + rl) * 512 + kc + quad * 8);
        }
        {
            int half = tid >> 7, rem = tid & 127;
            int row = rem >> 2, quad = rem & 3;
            const unsigned short* srcp = half ? Hbl : Hbh;
            bv = *(const uint4*)(srcp + (size_t)(b0 + row) * 512 + kc + quad * 8);
        }
        __syncthreads();
#pragma unroll
        for (int i = 0; i < 3; ++i) {
            int idx = tid + 256 * i;
            int half = idx >= 384;
            int rem = half ? idx - 384 : idx;
            int row = rem >> 2, quad = rem & 3;
            *(uint4*)&As[half][row][quad * 8] = av[i];
        }
        {
            int half = tid >> 7, rem = tid & 127;
            int row = rem >> 2, quad = rem & 3;
            *(uint4*)&Bs[half][row][quad * 8] = bv;
        }
        __syncthreads();
        bf16x8 bh = *(const bf16x8*)&Bs[0][bf * 16 + l15][l4 * 8];
        bf16x8 bl = *(const bf16x8*)&Bs[1][bf * 16 + l15][l4 * 8];
#pragma unroll
        for (int g = 0; g < 3; ++g) {
            bf16x8 ah = *(const bf16x8*)&As[0][g * 32 + jf * 16 + l15][l4 * 8];
            bf16x8 al = *(const bf16x8*)&As[1][g * 32 + jf * 16 + l15][l4 * 8];
            f32x4& ac = (g == 0 ? aR : (g == 1 ? aZ : aN));
            ac = __builtin_amdgcn_mfma_f32_16x16x32_bf16(ah, bh, ac, 0, 0, 0);
            ac = __builtin_amdgcn_mfma_f32_16x16x32_bf16(ah, bl, ac, 0, 0, 0);
            ac = __builtin_amdgcn_mfma_f32_16x16x32_bf16(al, bh, ac, 0, 0, 0);
        }
    }
#pragma unroll
    for (int r = 0; r < 4; ++r) {
        int jl = jf * 16 + l4 * 4 + r;
        int jrow = j0 + jl;
        int b = b0 + bf * 16 + l15;
        float ghr = aR[r] + bhh[jrow];
        float ghz = aZ[r] + bhh[512 + jrow];
        float ghn = aN[r] + bhh[1024 + jrow];
        float xr = xi[(size_t)jrow * 256 + b];
        float xz = xi[(size_t)(512 + jrow) * 256 + b];
        float xn = xi[(size_t)(1024 + jrow) * 256 + b];
        float hp = hprevf[(size_t)jrow * 256 + b];
        float rr = sigm(xr + ghr);
        float zz = sigm(xz + ghz);
        float nn = tanhf(xn + rr * ghn);
        float hv = (1.f - zz) * nn + zz * hp;
        hnewf[(size_t)jrow * 256 + b] = hv;
        hl[jl][bf * 16 + l15] = hv;
    }
    __syncthreads();
    {   // bf16 split + transpose to [b][k] rows
        int bl_ = tid >> 3;   // 0..31
        int kg = tid & 7;     // 0..7 -> 4 k each
        ushort4 hq, lq;
        unsigned short* hqp = (unsigned short*)&hq;
        unsigned short* lqp = (unsigned short*)&lq;
#pragma unroll
        for (int i = 0; i < 4; ++i) {
            float v = hl[kg * 4 + i][bl_];
            unsigned short hh = bf16_rne(v);
            hqp[i] = hh;
            lqp[i] = bf16_rne(v - bf16_tof(hh));
        }
        *(ushort4*)(Hnh + (size_t)(b0 + bl_) * 512 + j0 + kg * 4) = hq;
        *(ushort4*)(Hnl + (size_t)(b0 + bl_) * 512 + j0 + kg * 4) = lq;
    }
}

// x[t] -> bf16 split rows [b][k]
__device__ __forceinline__ void xc_block(int local, const float* __restrict__ x, int t,
    unsigned short* __restrict__ Xh, unsigned short* __restrict__ Xl) {
    int e = (local * 256 + threadIdx.x) * 16;
    int b = e >> 9, k0 = e & 511;
    const float* src = x + ((size_t)b * TT + t) * NN + k0;
#pragma unroll
    for (int q = 0; q < 4; ++q)
        conv4(src + q * 4, Xh + (size_t)b * 512 + k0 + q * 4,
              Xl + (size_t)b * 512 + k0 + q * 4);
}

// one pipelined step; tile->block maps keep each weight tile on one XCD (bi%8)
__device__ __forceinline__ void do_step(int s, int bi, const PA& a,
                                        unsigned char* smem) {
    if (bi < 128) {                       // REC0, t = s
        int t = s;
        if (t >= 0 && t <= 127) {
            int sp = (t - 1) & 1, sn = t & 1;
            int xx = bi & 7, idx = bi >> 3;
            int j0 = (xx * 2 + (idx & 1)) * 32, b0 = (idx >> 1) * 32;
            rec_block(j0, b0, a.W0hh_h, a.W0hh_l,
                      a.H0h + (size_t)sp * SLAB, a.H0l + (size_t)sp * SLAB,
                      a.xi0 + (size_t)sn * XSLAB, a.bhh0,
                      a.h0f + (size_t)sp * SLAB, a.h0f + (size_t)sn * SLAB,
                      a.H0h + (size_t)sn * SLAB, a.H0l + (size_t)sn * SLAB, smem);
        }
    } else if (bi < 256) {                // REC1, t = s-2
        int t = s - 2;
        if (t >= 0 && t <= 127) {
            int sp = (t - 1) & 1, sn = t & 1;
            int local = bi - 128;
            int xx = local & 7, idx = local >> 3;
            int j0 = (xx * 2 + (idx & 1)) * 32, b0 = (idx >> 1) * 32;
            rec_block(j0, b0, a.W1hh_h, a.W1hh_l,
                      a.H1h + (size_t)sp * SLAB, a.H1l + (size_t)sp * SLAB,
                      a.xi1 + (size_t)sn * XSLAB, a.bhh1,
                      a.h1f + (size_t)sp * SLAB, a.h1f + (size_t)sn * SLAB,
                      a.H1h + (size_t)sn * SLAB, a.H1l + (size_t)sn * SLAB, smem);
        }
    } else if (bi < 448) {                // XI1, t = s-1: xi1[t] = W1ih x h0bf[t]
        int t = s - 1;
        if (t >= 0 && t <= 127) {
            int sl = t & 1;
            int local = bi - 256;
            int xx = local & 7, idx = local >> 3;
            int g0 = (xx * 3 + idx % 3) * 64, b0 = (idx / 3) * 32;
            xi_block(g0, b0, a.W1ih_h, a.W1ih_l,
                     a.H0h + (size_t)sl * SLAB, a.H0l + (size_t)sl * SLAB,
                     a.bih1, a.xi1 + (size_t)sl * XSLAB, smem);
        }
    } else if (bi < 640) {                // XI0, t = s+1: xi0[t] = W0ih x Xbf[t]
        int t = s + 1;
        if (t >= 0 && t <= 127) {
            int sl = t & 1;
            int local = bi - 448;
            int xx = local & 7, idx = local >> 3;
            int g0 = (xx * 3 + idx % 3) * 64, b0 = (idx / 3) * 32;
            xi_block(g0, b0, a.W0ih_h, a.W0ih_l,
                     a.Xh + (size_t)sl * SLAB, a.Xl + (size_t)sl * SLAB,
                     a.bih0, a.xi0 + (size_t)sl * XSLAB, smem);
        }
    } else {                              // XC, t = s+2
        int t = s + 2;
        if (t >= 0 && t <= 127) {
            int sl = t & 1;
            xc_block(bi - 640, a.x, t,
                     a.Xh + (size_t)sl * SLAB, a.Xl + (size_t)sl * SLAB);
        }
    }
}

// weight convert + state zero, grid-strided over the whole grid
__device__ void conv_phase(int bi, const PA& a) {
    const int gt = bi * NTHR + threadIdx.x;
    const int NT = NBLK * NTHR;
    for (int base = gt * 4; base < G3 * HH; base += NT * 4) {
        conv4(a.Wih0 + base, a.W0ih_h + base, a.W0ih_l + base);
        conv4(a.Whh0 + base, a.W0hh_h + base, a.W0hh_l + base);
        conv4(a.Wih1 + base, a.W1ih_h + base, a.W1ih_l + base);
        conv4(a.Whh1 + base, a.W1hh_h + base, a.W1hh_l + base);
    }
    int i = gt;
    float4 z4 = {0.f, 0.f, 0.f, 0.f};
    uint4 zu = {0u, 0u, 0u, 0u};
    if (i < 32768)       ((float4*)(a.h0f + SLAB))[i] = z4;
    else if (i < 65536)  ((float4*)(a.h1f + SLAB))[i - 32768] = z4;
    else if (i < 81920)  ((uint4*)(a.H0h + SLAB))[i - 65536] = zu;
    else if (i < 98304)  ((uint4*)(a.H0l + SLAB))[i - 81920] = zu;
    else if (i < 114688) ((uint4*)(a.H1h + SLAB))[i - 98304] = zu;
    else if (i < 131072) ((uint4*)(a.H1l + SLAB))[i - 114688] = zu;
}

__global__ __launch_bounds__(256, 3) void gru_pipeline(PA a) {
    __shared__ __align__(16) unsigned char smem[25600];
    cg::grid_group grid = cg::this_grid();
    const int bi = blockIdx.x;
    conv_phase(bi, a);
    grid.sync();
    for (int s = -2; s <= 129; ++s) {
        do_step(s, bi, a, smem);
        grid.sync();
    }
}

// non-cooperative fallback: one step per launch
__global__ __launch_bounds__(256) void step_once(int s, PA a) {
    __shared__ __align__(16) unsigned char smem[25600];
    do_step(s, blockIdx.x, a, smem);
}

// ---- tail ------------------------------------------------------------------

__global__ __launch_bounds__(256) void hT_to_h(
    const float* __restrict__ hT, float* __restrict__ h) {
    __shared__ float tb[64][65];
    const int tid = threadIdx.x;
    const int k0 = blockIdx.x * 64, b0 = blockIdx.y * 64;
#pragma unroll
    for (int i = 0; i < 4; ++i) {
        int r = (tid >> 4) + 16 * i;
        int c = (tid & 15) * 4;
        float4 v = *(const float4*)(hT + (size_t)(k0 + r) * 256 + b0 + c);
        tb[c + 0][r] = v.x; tb[c + 1][r] = v.y; tb[c + 2][r] = v.z; tb[c + 3][r] = v.w;
    }
    __syncthreads();
#pragma unroll
    for (int i = 0; i < 4; ++i) {
        int r = (tid >> 4) + 16 * i;
        int c = (tid & 15) * 4;
        float4 v;
        v.x = tb[r][c]; v.y = tb[r][c + 1]; v.z = tb[r][c + 2]; v.w = tb[r][c + 3];
        *(float4*)(h + (size_t)(b0 + r) * 512 + k0 + c) = v;
    }
}

__device__ __forceinline__ float blockReduceSum(float v, float* tmp) {
    __syncthreads();
#pragma unroll
    for (int o = 32; o; o >>= 1) v += __shfl_down(v, o);
    if ((threadIdx.x & 63) == 0) tmp[threadIdx.x >> 6] = v;
    __syncthreads();
    if (threadIdx.x == 0) tmp[4] = tmp[0] + tmp[1] + tmp[2] + tmp[3];
    __syncthreads();
    return tmp[4];
}

__device__ __forceinline__ float blockReduceMax(float v, float* tmp) {
    __syncthreads();
#pragma unroll
    for (int o = 32; o; o >>= 1) v = fmaxf(v, __shfl_down(v, o));
    if ((threadIdx.x & 63) == 0) tmp[threadIdx.x >> 6] = v;
    __syncthreads();
    if (threadIdx.x == 0) tmp[4] = fmaxf(fmaxf(tmp[0], tmp[1]), fmaxf(tmp[2], tmp[3]));
    __syncthreads();
    return tmp[4];
}

__global__ __launch_bounds__(256) void head_kernel(
    const float* __restrict__ h1, const float* __restrict__ fcw,
    const float* __restrict__ fcb, float* __restrict__ out) {
    __shared__ __align__(16) float hrow[512];
    __shared__ float wv[512];
    __shared__ float ov[512];
    __shared__ float tmp[8];
    const int b = blockIdx.x, tid = threadIdx.x;
    hrow[tid]       = h1[(size_t)b * 512 + tid];
    hrow[tid + 256] = h1[(size_t)b * 512 + 256 + tid];
    __syncthreads();

    float s[2];
#pragma unroll
    for (int q = 0; q < 2; ++q) {
        int n = tid + q * 256;
        const float* wr = fcw + (size_t)n * 512;
        float acc = 0.f;
        for (int k = 0; k < 512; k += 4) {
            float4 wq = *(const float4*)(wr + k);
            acc += wq.x * hrow[k] + wq.y * hrow[k + 1] + wq.z * hrow[k + 2] + wq.w * hrow[k + 3];
        }
        float l = acc + fcb[n];
        s[q] = l / (1.f + expf(-l));
    }

    float mx = blockReduceMax(fmaxf(s[0], s[1]), tmp);
    float e0 = expf(s[0] - mx), e1 = expf(s[1] - mx);
    float sum = blockReduceSum(e0 + e1, tmp);
    float w0 = e0 / sum, w1 = e1 / sum;

    ov[tid] = w0;       ov[tid + 256] = w1;
    wv[tid]       = fminf(fmaxf(w0, 0.f), 0.1f);
    wv[tid + 256] = fminf(fmaxf(w1, 0.f), 0.1f);
    __syncthreads();

    for (int it = 0; it < 32; ++it) {
        float wc0 = wv[tid], wc1 = wv[tid + 256];
        float o0 = ov[tid], o1 = ov[tid + 256];
        float leftover = blockReduceSum((o0 - wc0) + (o1 - wc1), tmp);
        float n0 = (wc0 != 0.1f) ? wc0 : 0.f;
        float n1 = (wc1 != 0.1f) ? wc1 : 0.f;
        float denom = blockReduceSum(n0 + n1, tmp);
        float w20 = wc0 + leftover * n0 / denom;
        float w21 = wc1 + leftover * n1 / denom;
        float fl = ((w20 > 0.1f) || (w21 > 0.1f)) ? 1.f : 0.f;
        bool again = blockReduceSum(fl, tmp) > 0.f;
        __syncthreads();
        ov[tid] = w20; ov[tid + 256] = w21;
        wv[tid]       = again ? fminf(fmaxf(w20, 0.f), 0.1f) : w20;
        wv[tid + 256] = again ? fminf(fmaxf(w21, 0.f), 0.1f) : w21;
        __syncthreads();
        if (!again) break;
    }

    out[(size_t)b * 512 + tid]       = wv[tid];
    out[(size_t)b * 512 + 256 + tid] = wv[tid + 256];
}

extern "C" void kernel_launch(void* const* d_in, const int* in_sizes, int n_in,
                              void* d_out, int out_size, void* d_ws, size_t ws_size,
                              hipStream_t stream) {
    PA a;
    a.x    = (const float*)d_in[0];
    a.Wih0 = (const float*)d_in[1];
    a.Whh0 = (const float*)d_in[2];
    a.bih0 = (const float*)d_in[3];
    a.bhh0 = (const float*)d_in[4];
    a.Wih1 = (const float*)d_in[5];
    a.Whh1 = (const float*)d_in[6];
    a.bih1 = (const float*)d_in[7];
    a.bhh1 = (const float*)d_in[8];
    const float* fcw = (const float*)d_in[9];
    const float* fcb = (const float*)d_in[10];
    float* out = (float*)d_out;

    const size_t WHALF = (size_t)G3 * HH;
    unsigned short* base = (unsigned short*)d_ws;
    a.W0ih_h = base;
    a.W0ih_l = a.W0ih_h + WHALF;
    a.W0hh_h = a.W0ih_l + WHALF;
    a.W0hh_l = a.W0hh_h + WHALF;
    a.W1ih_h = a.W0hh_l + WHALF;
    a.W1ih_l = a.W1ih_h + WHALF;
    a.W1hh_h = a.W1ih_l + WHALF;
    a.W1hh_l = a.W1hh_h + WHALF;
    a.Xh  = a.W1hh_l + WHALF;
    a.Xl  = a.Xh + 2 * (size_t)SLAB;
    a.H0h = a.Xl + 2 * (size_t)SLAB;
    a.H0l = a.H0h + 2 * (size_t)SLAB;
    a.H1h = a.H0l + 2 * (size_t)SLAB;
    a.H1l = a.H1h + 2 * (size_t)SLAB;
    float* fbase = (float*)(a.H1l + 2 * (size_t)SLAB);
    a.xi0 = fbase;
    a.xi1 = a.xi0 + 2 * (size_t)XSLAB;
    a.h0f = a.xi1 + 2 * (size_t)XSLAB;
    a.h1f = a.h0f + 2 * (size_t)SLAB;
    float* h1n = a.h1f + 2 * (size_t)SLAB;

    void* kargs[] = { (void*)&a };
    hipError_t e = hipLaunchCooperativeKernel(gru_pipeline, dim3(NBLK), dim3(NTHR),
                                              kargs, 0u, stream);
    if (e != hipSuccess) {
        // fallback: per-step launches (same sections), classic prologue
        const int wn = G3 * HH;
        convert_split<<<wn / 1024, 256, 0, stream>>>(a.Wih0, a.W0ih_h, a.W0ih_l, wn);
        convert_split<<<wn / 1024, 256, 0, stream>>>(a.Whh0, a.W0hh_h, a.W0hh_l, wn);
        convert_split<<<wn / 1024, 256, 0, stream>>>(a.Wih1, a.W1ih_h, a.W1ih_l, wn);
        convert_split<<<wn / 1024, 256, 0, stream>>>(a.Whh1, a.W1hh_h, a.W1hh_l, wn);
        zero_kernel<<<SLAB / 256, 256, 0, stream>>>(a.h0f + SLAB, SLAB);
        zero_kernel<<<SLAB / 256, 256, 0, stream>>>(a.h1f + SLAB, SLAB);
        zero_kernel<<<(SLAB / 2) / 256, 256, 0, stream>>>((float*)(a.H0h + SLAB), SLAB / 2);
        zero_kernel<<<(SLAB / 2) / 256, 256, 0, stream>>>((float*)(a.H0l + SLAB), SLAB / 2);
        zero_kernel<<<(SLAB / 2) / 256, 256, 0, stream>>>((float*)(a.H1h + SLAB), SLAB / 2);
        zero_kernel<<<(SLAB / 2) / 256, 256, 0, stream>>>((float*)(a.H1l + SLAB), SLAB / 2);
        for (int s = -2; s <= 129; ++s)
            step_once<<<NBLK, NTHR, 0, stream>>>(s, a);
    }

    hT_to_h<<<dim3(8, 4), 256, 0, stream>>>(a.h1f + SLAB, h1n);
    head_kernel<<<BB, 256, 0, stream>>>(h1n, fcw, fcb, out);
}

// Round 6
// 4861.082 us; speedup vs baseline: 3.6757x; 3.6757x over previous
//
#include <hip/hip_runtime.h>
#include <math.h>

#define BB 256
#define TT 128
#define NN 512
#define HH 512
#define G3 1536
#define SLAB (HH * BB)     // 131072 elems: one [512][256] / [256][512] slab
#define XSLAB (G3 * BB)    // 393216 floats: one [1536][256] xi slab
#define NBLK 672
#define NTHR 256

typedef __attribute__((ext_vector_type(8))) short bf16x8;   // 8 bf16 = 4 VGPRs
typedef __attribute__((ext_vector_type(4))) float f32x4;

struct PA {
    const float* x;
    const float* bih0; const float* bhh0; const float* bih1; const float* bhh1;
    unsigned short *W0ih_h, *W0ih_l, *W0hh_h, *W0hh_l;
    unsigned short *W1ih_h, *W1ih_l, *W1hh_h, *W1hh_l;
    unsigned short *Xh, *Xl, *H0h, *H0l, *H1h, *H1l;
    float *xi0, *xi1, *h0f, *h1f;
};

__device__ __forceinline__ unsigned short bf16_rne(float f) {
    union { float f; unsigned int u; } v; v.f = f;
    unsigned int r = (v.u + 0x7fffu + ((v.u >> 16) & 1u)) >> 16;
    return (unsigned short)r;
}
__device__ __forceinline__ float bf16_tof(unsigned short h) {
    union { float f; unsigned int u; } v; v.u = ((unsigned int)h) << 16;
    return v.f;
}
__device__ __forceinline__ float sigm(float v) { return 1.f / (1.f + expf(-v)); }

__device__ __forceinline__ void conv4(const float* src, unsigned short* dh,
                                      unsigned short* dl) {
    float4 v = *(const float4*)src;
    float f[4] = {v.x, v.y, v.z, v.w};
    ushort4 h, l;
    unsigned short* hp = (unsigned short*)&h;
    unsigned short* lp = (unsigned short*)&l;
#pragma unroll
    for (int q = 0; q < 4; ++q) {
        unsigned short hh = bf16_rne(f[q]);
        hp[q] = hh;
        lp[q] = bf16_rne(f[q] - bf16_tof(hh));
    }
    *(ushort4*)dh = h;
    *(ushort4*)dl = l;
}

__global__ void zero_kernel(float* p, int n) {
    int i = blockIdx.x * blockDim.x + threadIdx.x;
    if (i < n) p[i] = 0.f;
}

__global__ __launch_bounds__(256) void convert_split(
    const float* __restrict__ in, unsigned short* __restrict__ hi,
    unsigned short* __restrict__ lo, int n) {
    int i = (blockIdx.x * 256 + threadIdx.x) * 4;
    if (i >= n) return;
    conv4(in + i, hi + i, lo + i);
}

// ---- pipeline sections ----------------------------------------------------

// xi GEMM: out[g][b] = sum_k W[g][k]*Brow[b][k] + bias[g]; tile 64g x 32b
__device__ __forceinline__ void xi_block(int g0, int b0,
    const unsigned short* __restrict__ Wh, const unsigned short* __restrict__ Wl,
    const unsigned short* __restrict__ Bh, const unsigned short* __restrict__ Bl,
    const float* __restrict__ bias, float* __restrict__ out, unsigned char* smem) {
    unsigned short (*As)[64][40] = (unsigned short (*)[64][40])smem;             // 10240 B
    unsigned short (*Bs)[32][40] = (unsigned short (*)[32][40])(smem + 10240);   // 5120 B
    const int tid = threadIdx.x;
    const int lane = tid & 63, w = tid >> 6;
    const int l15 = lane & 15, l4 = lane >> 4;
    f32x4 acc0 = {0, 0, 0, 0}, acc1 = {0, 0, 0, 0};
    for (int kc = 0; kc < 512; kc += 32) {
        uint4 av[2], bv;
#pragma unroll
        for (int i = 0; i < 2; ++i) {
            int idx = tid + 256 * i;
            int half = idx >> 8, rem = idx & 255;
            int row = rem >> 2, quad = rem & 3;
            const unsigned short* srcp = half ? Wl : Wh;
            av[i] = *(const uint4*)(srcp + (size_t)(g0 + row) * 512 + kc + quad * 8);
        }
        {
            int half = tid >> 7, rem = tid & 127;
            int row = rem >> 2, quad = rem & 3;
            const unsigned short* srcp = half ? Bl : Bh;
            bv = *(const uint4*)(srcp + (size_t)(b0 + row) * 512 + kc + quad * 8);
        }
        __syncthreads();
#pragma unroll
        for (int i = 0; i < 2; ++i) {
            int idx = tid + 256 * i;
            int half = idx >> 8, rem = idx & 255;
            int row = rem >> 2, quad = rem & 3;
            *(uint4*)&As[half][row][quad * 8] = av[i];
        }
        {
            int half = tid >> 7, rem = tid & 127;
            int row = rem >> 2, quad = rem & 3;
            *(uint4*)&Bs[half][row][quad * 8] = bv;
        }
        __syncthreads();
        bf16x8 ah = *(const bf16x8*)&As[0][w * 16 + l15][l4 * 8];
        bf16x8 al = *(const bf16x8*)&As[1][w * 16 + l15][l4 * 8];
        bf16x8 bh0 = *(const bf16x8*)&Bs[0][l15][l4 * 8];
        bf16x8 bl0 = *(const bf16x8*)&Bs[1][l15][l4 * 8];
        bf16x8 bh1 = *(const bf16x8*)&Bs[0][16 + l15][l4 * 8];
        bf16x8 bl1 = *(const bf16x8*)&Bs[1][16 + l15][l4 * 8];
        acc0 = __builtin_amdgcn_mfma_f32_16x16x32_bf16(ah, bh0, acc0, 0, 0, 0);
        acc0 = __builtin_amdgcn_mfma_f32_16x16x32_bf16(ah, bl0, acc0, 0, 0, 0);
        acc0 = __builtin_amdgcn_mfma_f32_16x16x32_bf16(al, bh0, acc0, 0, 0, 0);
        acc1 = __builtin_amdgcn_mfma_f32_16x16x32_bf16(ah, bh1, acc1, 0, 0, 0);
        acc1 = __builtin_amdgcn_mfma_f32_16x16x32_bf16(ah, bl1, acc1, 0, 0, 0);
        acc1 = __builtin_amdgcn_mfma_f32_16x16x32_bf16(al, bh1, acc1, 0, 0, 0);
    }
#pragma unroll
    for (int r = 0; r < 4; ++r) {
        int g = g0 + w * 16 + l4 * 4 + r;
        float bvs = bias[g];
        out[(size_t)g * 256 + b0 + l15] = acc0[r] + bvs;
        out[(size_t)g * 256 + b0 + 16 + l15] = acc1[r] + bvs;
    }
}

// recurrent step: gh = h@Whh^T (+bhh), gates, h-update; tile 32j(x3 gates) x 32b
__device__ __forceinline__ void rec_block(int j0, int b0,
    const unsigned short* __restrict__ Wh, const unsigned short* __restrict__ Wl,
    const unsigned short* __restrict__ Hbh, const unsigned short* __restrict__ Hbl,
    const float* __restrict__ xi, const float* __restrict__ bhh,
    const float* __restrict__ hprevf, float* __restrict__ hnewf,
    unsigned short* __restrict__ Hnh, unsigned short* __restrict__ Hnl,
    unsigned char* smem) {
    unsigned short (*As)[96][40] = (unsigned short (*)[96][40])smem;             // 15360 B
    unsigned short (*Bs)[32][40] = (unsigned short (*)[32][40])(smem + 15360);   // 5120 B
    float (*hl)[36] = (float (*)[36])(smem + 20480);                             // 4608 B
    const int tid = threadIdx.x;
    const int lane = tid & 63, w = tid >> 6;
    const int l15 = lane & 15, l4 = lane >> 4;
    const int jf = w >> 1, bf = w & 1;
    f32x4 aR = {0, 0, 0, 0}, aZ = aR, aN = aR;
    for (int kc = 0; kc < 512; kc += 32) {
        uint4 av[3], bv;
#pragma unroll
        for (int i = 0; i < 3; ++i) {
            int idx = tid + 256 * i;                 // 0..767
            int half = idx >= 384;
            int rem = half ? idx - 384 : idx;
            int row = rem >> 2, quad = rem & 3;      // row 0..95
            int gate = row >> 5, rl = row & 31;
            const unsigned short* srcp = half ? Wl : Wh;
            av[i] = *(const uint4*)(srcp + (size_t)(gate * 512 + j0 + rl) * 512 + kc + quad * 8);
        }
        {
            int half = tid >> 7, rem = tid & 127;
            int row = rem >> 2, quad = rem & 3;
            const unsigned short* srcp = half ? Hbl : Hbh;
            bv = *(const uint4*)(srcp + (size_t)(b0 + row) * 512 + kc + quad * 8);
        }
        __syncthreads();
#pragma unroll
        for (int i = 0; i < 3; ++i) {
            int idx = tid + 256 * i;
            int half = idx >= 384;
            int rem = half ? idx - 384 : idx;
            int row = rem >> 2, quad = rem & 3;
            *(uint4*)&As[half][row][quad * 8] = av[i];
        }
        {
            int half = tid >> 7, rem = tid & 127;
            int row = rem >> 2, quad = rem & 3;
            *(uint4*)&Bs[half][row][quad * 8] = bv;
        }
        __syncthreads();
        bf16x8 bh = *(const bf16x8*)&Bs[0][bf * 16 + l15][l4 * 8];
        bf16x8 bl = *(const bf16x8*)&Bs[1][bf * 16 + l15][l4 * 8];
#pragma unroll
        for (int g = 0; g < 3; ++g) {
            bf16x8 ah = *(const bf16x8*)&As[0][g * 32 + jf * 16 + l15][l4 * 8];
            bf16x8 al = *(const bf16x8*)&As[1][g * 32 + jf * 16 + l15][l4 * 8];
            f32x4& ac = (g == 0 ? aR : (g == 1 ? aZ : aN));
            ac = __builtin_amdgcn_mfma_f32_16x16x32_bf16(ah, bh, ac, 0, 0, 0);
            ac = __builtin_amdgcn_mfma_f32_16x16x32_bf16(ah, bl, ac, 0, 0, 0);
            ac = __builtin_amdgcn_mfma_f32_16x16x32_bf16(al, bh, ac, 0, 0, 0);
        }
    }
#pragma unroll
    for (int r = 0; r < 4; ++r) {
        int jl = jf * 16 + l4 * 4 + r;
        int jrow = j0 + jl;
        int b = b0 + bf * 16 + l15;
        float ghr = aR[r] + bhh[jrow];
        float ghz = aZ[r] + bhh[512 + jrow];
        float ghn = aN[r] + bhh[1024 + jrow];
        float xr = xi[(size_t)jrow * 256 + b];
        float xz = xi[(size_t)(512 + jrow) * 256 + b];
        float xn = xi[(size_t)(1024 + jrow) * 256 + b];
        float hp = hprevf[(size_t)jrow * 256 + b];
        float rr = sigm(xr + ghr);
        float zz = sigm(xz + ghz);
        float nn = tanhf(xn + rr * ghn);
        float hv = (1.f - zz) * nn + zz * hp;
        hnewf[(size_t)jrow * 256 + b] = hv;
        hl[jl][bf * 16 + l15] = hv;
    }
    __syncthreads();
    {   // bf16 split + transpose to [b][k] rows
        int bl_ = tid >> 3;   // 0..31
        int kg = tid & 7;     // 0..7 -> 4 k each
        ushort4 hq, lq;
        unsigned short* hqp = (unsigned short*)&hq;
        unsigned short* lqp = (unsigned short*)&lq;
#pragma unroll
        for (int i = 0; i < 4; ++i) {
            float v = hl[kg * 4 + i][bl_];
            unsigned short hh = bf16_rne(v);
            hqp[i] = hh;
            lqp[i] = bf16_rne(v - bf16_tof(hh));
        }
        *(ushort4*)(Hnh + (size_t)(b0 + bl_) * 512 + j0 + kg * 4) = hq;
        *(ushort4*)(Hnl + (size_t)(b0 + bl_) * 512 + j0 + kg * 4) = lq;
    }
}

// x[t] -> bf16 split rows [b][k]
__device__ __forceinline__ void xc_block(int local, const float* __restrict__ x, int t,
    unsigned short* __restrict__ Xh, unsigned short* __restrict__ Xl) {
    int e = (local * 256 + threadIdx.x) * 16;
    int b = e >> 9, k0 = e & 511;
    const float* src = x + ((size_t)b * TT + t) * NN + k0;
#pragma unroll
    for (int q = 0; q < 4; ++q)
        conv4(src + q * 4, Xh + (size_t)b * 512 + k0 + q * 4,
              Xl + (size_t)b * 512 + k0 + q * 4);
}

// one pipelined step; tile->block maps keep each weight panel on one XCD (bi%8)
__device__ __forceinline__ void do_step(int s, int bi, const PA& a,
                                        unsigned char* smem) {
    if (bi < 128) {                       // REC0, t = s
        int t = s;
        if (t >= 0 && t <= 127) {
            int sp = (t - 1) & 1, sn = t & 1;
            int xx = bi & 7, idx = bi >> 3;
            int j0 = (xx * 2 + (idx & 1)) * 32, b0 = (idx >> 1) * 32;
            rec_block(j0, b0, a.W0hh_h, a.W0hh_l,
                      a.H0h + (size_t)sp * SLAB, a.H0l + (size_t)sp * SLAB,
                      a.xi0 + (size_t)sn * XSLAB, a.bhh0,
                      a.h0f + (size_t)sp * SLAB, a.h0f + (size_t)sn * SLAB,
                      a.H0h + (size_t)sn * SLAB, a.H0l + (size_t)sn * SLAB, smem);
        }
    } else if (bi < 256) {                // REC1, t = s-2
        int t = s - 2;
        if (t >= 0 && t <= 127) {
            int sp = (t - 1) & 1, sn = t & 1;
            int local = bi - 128;
            int xx = local & 7, idx = local >> 3;
            int j0 = (xx * 2 + (idx & 1)) * 32, b0 = (idx >> 1) * 32;
            rec_block(j0, b0, a.W1hh_h, a.W1hh_l,
                      a.H1h + (size_t)sp * SLAB, a.H1l + (size_t)sp * SLAB,
                      a.xi1 + (size_t)sn * XSLAB, a.bhh1,
                      a.h1f + (size_t)sp * SLAB, a.h1f + (size_t)sn * SLAB,
                      a.H1h + (size_t)sn * SLAB, a.H1l + (size_t)sn * SLAB, smem);
        }
    } else if (bi < 448) {                // XI1, t = s-1: xi1[t] = W1ih x h0bf[t]
        int t = s - 1;
        if (t >= 0 && t <= 127) {
            int sl = t & 1;
            int local = bi - 256;
            int xx = local & 7, idx = local >> 3;
            int g0 = (xx * 3 + idx % 3) * 64, b0 = (idx / 3) * 32;
            xi_block(g0, b0, a.W1ih_h, a.W1ih_l,
                     a.H0h + (size_t)sl * SLAB, a.H0l + (size_t)sl * SLAB,
                     a.bih1, a.xi1 + (size_t)sl * XSLAB, smem);
        }
    } else if (bi < 640) {                // XI0, t = s+1: xi0[t] = W0ih x Xbf[t]
        int t = s + 1;
        if (t >= 0 && t <= 127) {
            int sl = t & 1;
            int local = bi - 448;
            int xx = local & 7, idx = local >> 3;
            int g0 = (xx * 3 + idx % 3) * 64, b0 = (idx / 3) * 32;
            xi_block(g0, b0, a.W0ih_h, a.W0ih_l,
                     a.Xh + (size_t)sl * SLAB, a.Xl + (size_t)sl * SLAB,
                     a.bih0, a.xi0 + (size_t)sl * XSLAB, smem);
        }
    } else {                              // XC, t = s+2
        int t = s + 2;
        if (t >= 0 && t <= 127) {
            int sl = t & 1;
            xc_block(bi - 640, a.x, t,
                     a.Xh + (size_t)sl * SLAB, a.Xl + (size_t)sl * SLAB);
        }
    }
}

__global__ __launch_bounds__(256) void step_once(int s, PA a) {
    __shared__ __align__(16) unsigned char smem[25600];
    do_step(s, blockIdx.x, a, smem);
}

// ---- tail ------------------------------------------------------------------

__global__ __launch_bounds__(256) void hT_to_h(
    const float* __restrict__ hT, float* __restrict__ h) {
    __shared__ float tb[64][65];
    const int tid = threadIdx.x;
    const int k0 = blockIdx.x * 64, b0 = blockIdx.y * 64;
#pragma unroll
    for (int i = 0; i < 4; ++i) {
        int r = (tid >> 4) + 16 * i;
        int c = (tid & 15) * 4;
        float4 v = *(const float4*)(hT + (size_t)(k0 + r) * 256 + b0 + c);
        tb[c + 0][r] = v.x; tb[c + 1][r] = v.y; tb[c + 2][r] = v.z; tb[c + 3][r] = v.w;
    }
    __syncthreads();
#pragma unroll
    for (int i = 0; i < 4; ++i) {
        int r = (tid >> 4) + 16 * i;
        int c = (tid & 15) * 4;
        float4 v;
        v.x = tb[r][c]; v.y = tb[r][c + 1]; v.z = tb[r][c + 2]; v.w = tb[r][c + 3];
        *(float4*)(h + (size_t)(b0 + r) * 512 + k0 + c) = v;
    }
}

__device__ __forceinline__ float blockReduceSum(float v, float* tmp) {
    __syncthreads();
#pragma unroll
    for (int o = 32; o; o >>= 1) v += __shfl_down(v, o);
    if ((threadIdx.x & 63) == 0) tmp[threadIdx.x >> 6] = v;
    __syncthreads();
    if (threadIdx.x == 0) tmp[4] = tmp[0] + tmp[1] + tmp[2] + tmp[3];
    __syncthreads();
    return tmp[4];
}

__device__ __forceinline__ float blockReduceMax(float v, float* tmp) {
    __syncthreads();
#pragma unroll
    for (int o = 32; o; o >>= 1) v = fmaxf(v, __shfl_down(v, o));
    if ((threadIdx.x & 63) == 0) tmp[threadIdx.x >> 6] = v;
    __syncthreads();
    if (threadIdx.x == 0) tmp[4] = fmaxf(fmaxf(tmp[0], tmp[1]), fmaxf(tmp[2], tmp[3]));
    __syncthreads();
    return tmp[4];
}

__global__ __launch_bounds__(256) void head_kernel(
    const float* __restrict__ h1, const float* __restrict__ fcw,
    const float* __restrict__ fcb, float* __restrict__ out) {
    __shared__ __align__(16) float hrow[512];
    __shared__ float wv[512];
    __shared__ float ov[512];
    __shared__ float tmp[8];
    const int b = blockIdx.x, tid = threadIdx.x;
    hrow[tid]       = h1[(size_t)b * 512 + tid];
    hrow[tid + 256] = h1[(size_t)b * 512 + 256 + tid];
    __syncthreads();

    float s[2];
#pragma unroll
    for (int q = 0; q < 2; ++q) {
        int n = tid + q * 256;
        const float* wr = fcw + (size_t)n * 512;
        float acc = 0.f;
        for (int k = 0; k < 512; k += 4) {
            float4 wq = *(const float4*)(wr + k);
            acc += wq.x * hrow[k] + wq.y * hrow[k + 1] + wq.z * hrow[k + 2] + wq.w * hrow[k + 3];
        }
        float l = acc + fcb[n];
        s[q] = l / (1.f + expf(-l));
    }

    float mx = blockReduceMax(fmaxf(s[0], s[1]), tmp);
    float e0 = expf(s[0] - mx), e1 = expf(s[1] - mx);
    float sum = blockReduceSum(e0 + e1, tmp);
    float w0 = e0 / sum, w1 = e1 / sum;

    ov[tid] = w0;       ov[tid + 256] = w1;
    wv[tid]       = fminf(fmaxf(w0, 0.f), 0.1f);
    wv[tid + 256] = fminf(fmaxf(w1, 0.f), 0.1f);
    __syncthreads();

    for (int it = 0; it < 32; ++it) {
        float wc0 = wv[tid], wc1 = wv[tid + 256];
        float o0 = ov[tid], o1 = ov[tid + 256];
        float leftover = blockReduceSum((o0 - wc0) + (o1 - wc1), tmp);
        float n0 = (wc0 != 0.1f) ? wc0 : 0.f;
        float n1 = (wc1 != 0.1f) ? wc1 : 0.f;
        float denom = blockReduceSum(n0 + n1, tmp);
        float w20 = wc0 + leftover * n0 / denom;
        float w21 = wc1 + leftover * n1 / denom;
        float fl = ((w20 > 0.1f) || (w21 > 0.1f)) ? 1.f : 0.f;
        bool again = blockReduceSum(fl, tmp) > 0.f;
        __syncthreads();
        ov[tid] = w20; ov[tid + 256] = w21;
        wv[tid]       = again ? fminf(fmaxf(w20, 0.f), 0.1f) : w20;
        wv[tid + 256] = again ? fminf(fmaxf(w21, 0.f), 0.1f) : w21;
        __syncthreads();
        if (!again) break;
    }

    out[(size_t)b * 512 + tid]       = wv[tid];
    out[(size_t)b * 512 + 256 + tid] = wv[tid + 256];
}

extern "C" void kernel_launch(void* const* d_in, const int* in_sizes, int n_in,
                              void* d_out, int out_size, void* d_ws, size_t ws_size,
                              hipStream_t stream) {
    const float* Wih0 = (const float*)d_in[1];
    const float* Whh0 = (const float*)d_in[2];
    const float* Wih1 = (const float*)d_in[5];
    const float* Whh1 = (const float*)d_in[6];
    const float* fcw = (const float*)d_in[9];
    const float* fcb = (const float*)d_in[10];
    float* out = (float*)d_out;

    PA a;
    a.x    = (const float*)d_in[0];
    a.bih0 = (const float*)d_in[3];
    a.bhh0 = (const float*)d_in[4];
    a.bih1 = (const float*)d_in[7];
    a.bhh1 = (const float*)d_in[8];

    const size_t WHALF = (size_t)G3 * HH;
    unsigned short* base = (unsigned short*)d_ws;
    a.W0ih_h = base;
    a.W0ih_l = a.W0ih_h + WHALF;
    a.W0hh_h = a.W0ih_l + WHALF;
    a.W0hh_l = a.W0hh_h + WHALF;
    a.W1ih_h = a.W0hh_l + WHALF;
    a.W1ih_l = a.W1ih_h + WHALF;
    a.W1hh_h = a.W1ih_l + WHALF;
    a.W1hh_l = a.W1hh_h + WHALF;
    a.Xh  = a.W1hh_l + WHALF;
    a.Xl  = a.Xh + 2 * (size_t)SLAB;
    a.H0h = a.Xl + 2 * (size_t)SLAB;
    a.H0l = a.H0h + 2 * (size_t)SLAB;
    a.H1h = a.H0l + 2 * (size_t)SLAB;
    a.H1l = a.H1h + 2 * (size_t)SLAB;
    float* fbase = (float*)(a.H1l + 2 * (size_t)SLAB);
    a.xi0 = fbase;
    a.xi1 = a.xi0 + 2 * (size_t)XSLAB;
    a.h0f = a.xi1 + 2 * (size_t)XSLAB;
    a.h1f = a.h0f + 2 * (size_t)SLAB;
    float* h1n = a.h1f + 2 * (size_t)SLAB;

    const int wn = G3 * HH;
    convert_split<<<wn / 1024, 256, 0, stream>>>(Wih0, a.W0ih_h, a.W0ih_l, wn);
    convert_split<<<wn / 1024, 256, 0, stream>>>(Whh0, a.W0hh_h, a.W0hh_l, wn);
    convert_split<<<wn / 1024, 256, 0, stream>>>(Wih1, a.W1ih_h, a.W1ih_l, wn);
    convert_split<<<wn / 1024, 256, 0, stream>>>(Whh1, a.W1hh_h, a.W1hh_l, wn);
    zero_kernel<<<SLAB / 256, 256, 0, stream>>>(a.h0f + SLAB, SLAB);
    zero_kernel<<<SLAB / 256, 256, 0, stream>>>(a.h1f + SLAB, SLAB);
    zero_kernel<<<(SLAB / 2) / 256, 256, 0, stream>>>((float*)(a.H0h + SLAB), SLAB / 2);
    zero_kernel<<<(SLAB / 2) / 256, 256, 0, stream>>>((float*)(a.H0l + SLAB), SLAB / 2);
    zero_kernel<<<(SLAB / 2) / 256, 256, 0, stream>>>((float*)(a.H1h + SLAB), SLAB / 2);
    zero_kernel<<<(SLAB / 2) / 256, 256, 0, stream>>>((float*)(a.H1l + SLAB), SLAB / 2);

    for (int s = -2; s <= 129; ++s)
        step_once<<<NBLK, NTHR, 0, stream>>>(s, a);

    hT_to_h<<<dim3(8, 4), 256, 0, stream>>>(a.h1f + SLAB, h1n);
    head_kernel<<<BB, 256, 0, stream>>>(h1n, fcw, fcb, out);
}

// Round 7
// 3498.273 us; speedup vs baseline: 5.1076x; 1.3896x over previous
//
#include <hip/hip_runtime.h>
#include <math.h>

#define BB 256
#define TT 128
#define NN 512
#define HH 512
#define G3 1536
#define SLAB (HH * BB)     // 131072 floats: one [512][256] k-major state slab
#define XSLAB (G3 * BB)    // 393216 floats: one [1536][256] xi slab
#define CH 16              // timesteps per xi0 chunk

typedef __attribute__((ext_vector_type(8))) short bf16x8;
typedef __attribute__((ext_vector_type(4))) float f32x4;

__device__ __forceinline__ unsigned short bf16_rne(float f) {
    union { float f; unsigned int u; } v; v.f = f;
    unsigned int r = (v.u + 0x7fffu + ((v.u >> 16) & 1u)) >> 16;
    return (unsigned short)r;
}
__device__ __forceinline__ float bf16_tof(unsigned short h) {
    union { float f; unsigned int u; } v; v.u = ((unsigned int)h) << 16;
    return v.f;
}
__device__ __forceinline__ float sigm(float v) { return 1.f / (1.f + expf(-v)); }
__device__ __forceinline__ void fma4(float4& a, float q, const float4& v) {
    a.x += q * v.x; a.y += q * v.y; a.z += q * v.z; a.w += q * v.w;
}

__global__ void zero_kernel(float* p, int n) {
    int i = blockIdx.x * blockDim.x + threadIdx.x;
    if (i < n) p[i] = 0.f;
}

// fp32 -> hi/lo bf16 split (for W0ih only)
__global__ __launch_bounds__(256) void convert_split(
    const float* __restrict__ in, unsigned short* __restrict__ hi,
    unsigned short* __restrict__ lo, int n) {
    int i = (blockIdx.x * 256 + threadIdx.x) * 4;
    if (i >= n) return;
    float4 v = *(const float4*)(in + i);
    float f[4] = {v.x, v.y, v.z, v.w};
    ushort4 h, l;
    unsigned short* hp = (unsigned short*)&h;
    unsigned short* lp = (unsigned short*)&l;
#pragma unroll
    for (int q = 0; q < 4; ++q) {
        unsigned short hh = bf16_rne(f[q]);
        hp[q] = hh;
        lp[q] = bf16_rne(f[q] - bf16_tof(hh));
    }
    *(ushort4*)(hi + i) = h;
    *(ushort4*)(lo + i) = l;
}

__device__ __forceinline__ void split8(float4 a, float4 b, uint4& hi, uint4& lo) {
    float f[8] = {a.x, a.y, a.z, a.w, b.x, b.y, b.z, b.w};
    unsigned short hs[8], ls[8];
#pragma unroll
    for (int q = 0; q < 8; ++q) {
        unsigned short h = bf16_rne(f[q]);
        hs[q] = h;
        ls[q] = bf16_rne(f[q] - bf16_tof(h));
    }
    hi = *(uint4*)hs;
    lo = *(uint4*)ls;
}

// xi0 chunk GEMM: out[tl][g][b] = sum_k W0ih[g][k]*x[b][t0+tl][k] + bih0[g]
// 128g x 128n tile (n = tl*256+b), 4 waves, split-bf16 3-term MFMA.
// B staged directly from fp32 x with inline hi/lo conversion.
__global__ __launch_bounds__(256) void xi_mfma_x(
    const unsigned short* __restrict__ Wh, const unsigned short* __restrict__ Wl,
    const float* __restrict__ x, int t0,
    const float* __restrict__ bias, float* __restrict__ out) {
    __shared__ unsigned short As[2][128][40];
    __shared__ unsigned short Bs[2][128][40];
    const int tid = threadIdx.x;
    const int n0 = blockIdx.x * 128;      // n-tile fast => XCD window shares A-panels
    const int g0 = blockIdx.y * 128;
    const int tl = n0 >> 8, b0 = n0 & 255;
    const int tg = t0 + tl;
    const int w = tid >> 6, lane = tid & 63;
    const int wg = (w >> 1) * 64, wb = (w & 1) * 64;
    const int l15 = lane & 15, l4 = lane >> 4;
    const int sr = tid >> 2, sc = (tid & 3) * 8;

    f32x4 acc[4][4] = {};
    for (int kc = 0; kc < 512; kc += 32) {
        uint4 a0 = *(const uint4*)(Wh + (size_t)(g0 + sr) * 512 + kc + sc);
        uint4 a1 = *(const uint4*)(Wh + (size_t)(g0 + 64 + sr) * 512 + kc + sc);
        uint4 a2 = *(const uint4*)(Wl + (size_t)(g0 + sr) * 512 + kc + sc);
        uint4 a3 = *(const uint4*)(Wl + (size_t)(g0 + 64 + sr) * 512 + kc + sc);
        const float* xr0 = x + ((size_t)(b0 + sr) * TT + tg) * NN + kc + sc;
        const float* xr1 = x + ((size_t)(b0 + 64 + sr) * TT + tg) * NN + kc + sc;
        float4 f00 = *(const float4*)xr0, f01 = *(const float4*)(xr0 + 4);
        float4 f10 = *(const float4*)xr1, f11 = *(const float4*)(xr1 + 4);
        uint4 bh0_, bl0_, bh1_, bl1_;
        split8(f00, f01, bh0_, bl0_);
        split8(f10, f11, bh1_, bl1_);
        __syncthreads();   // previous iteration's frag reads done
        *(uint4*)&As[0][sr][sc] = a0;      *(uint4*)&As[0][64 + sr][sc] = a1;
        *(uint4*)&As[1][sr][sc] = a2;      *(uint4*)&As[1][64 + sr][sc] = a3;
        *(uint4*)&Bs[0][sr][sc] = bh0_;    *(uint4*)&Bs[0][64 + sr][sc] = bh1_;
        *(uint4*)&Bs[1][sr][sc] = bl0_;    *(uint4*)&Bs[1][64 + sr][sc] = bl1_;
        __syncthreads();
        bf16x8 ah[4], al[4], bh[4], bl[4];
#pragma unroll
        for (int i = 0; i < 4; ++i) {
            ah[i] = *(const bf16x8*)&As[0][wg + 16 * i + l15][l4 * 8];
            al[i] = *(const bf16x8*)&As[1][wg + 16 * i + l15][l4 * 8];
            bh[i] = *(const bf16x8*)&Bs[0][wb + 16 * i + l15][l4 * 8];
            bl[i] = *(const bf16x8*)&Bs[1][wb + 16 * i + l15][l4 * 8];
        }
#pragma unroll
        for (int i = 0; i < 4; ++i)
#pragma unroll
            for (int j = 0; j < 4; ++j) {
                acc[i][j] = __builtin_amdgcn_mfma_f32_16x16x32_bf16(ah[i], bh[j], acc[i][j], 0, 0, 0);
                acc[i][j] = __builtin_amdgcn_mfma_f32_16x16x32_bf16(ah[i], bl[j], acc[i][j], 0, 0, 0);
                acc[i][j] = __builtin_amdgcn_mfma_f32_16x16x32_bf16(al[i], bh[j], acc[i][j], 0, 0, 0);
            }
    }
    float* op = out + (size_t)tl * XSLAB;
#pragma unroll
    for (int i = 0; i < 4; ++i) {
        int gbase = g0 + wg + 16 * i + l4 * 4;
#pragma unroll
        for (int r = 0; r < 4; ++r) {
            float bv = bias[gbase + r];
#pragma unroll
            for (int j = 0; j < 4; ++j)
                op[(size_t)(gbase + r) * 256 + b0 + wb + 16 * j + l15] = acc[i][j][r] + bv;
        }
    }
}

// One step: blocks 0-255 = rec0(t=s) [r3's barrier-free fp32 rec];
// blocks 256-511 = rec1-fused(t=s-1): gh1 = Whh1*h1 AND xi1 = Wih1*h0 in one pass.
__global__ __launch_bounds__(512) void fused_step(
    int s, const float* __restrict__ xiT,
    const float* __restrict__ Whh0, const float* __restrict__ bhh0,
    const float* __restrict__ Wih1, const float* __restrict__ Whh1,
    const float* __restrict__ bih1, const float* __restrict__ bhh1,
    float* __restrict__ h0f, float* __restrict__ h1f) {
    __shared__ f32x4 red[7][64][6];
    const int tid = threadIdx.x;
    const int b4 = tid & 63;
    const int kq = __builtin_amdgcn_readfirstlane(tid >> 6);  // 0..7 wave-uniform

    if (blockIdx.x < 256) {
        // ---------------- rec0: layer-0 step t = s ----------------
        int t = s;
        if (t > 127) return;
        const float* hTprev = h0f + (size_t)((t - 1) & 1) * SLAB;
        float* hTnext = h0f + (size_t)(t & 1) * SLAB;
        const int j0 = blockIdx.x * 2;
        const float* w0 = Whh0 + (size_t)(j0)*512 + kq * 64;
        const float* w1 = Whh0 + (size_t)(j0 + 1) * 512 + kq * 64;
        const float* w2 = Whh0 + (size_t)(512 + j0) * 512 + kq * 64;
        const float* w3 = Whh0 + (size_t)(513 + j0) * 512 + kq * 64;
        const float* w4 = Whh0 + (size_t)(1024 + j0) * 512 + kq * 64;
        const float* w5 = Whh0 + (size_t)(1025 + j0) * 512 + kq * 64;
        const float4* hp = (const float4*)hTprev + (size_t)kq * 64 * 64 + b4;

        float4 ar0 = {0, 0, 0, 0}, ar1 = ar0, az0 = ar0, az1 = ar0, an0 = ar0, an1 = ar0;
#pragma unroll 8
        for (int k = 0; k < 64; ++k) {
            float4 hv = hp[(size_t)k * 64];
            fma4(ar0, w0[k], hv); fma4(ar1, w1[k], hv);
            fma4(az0, w2[k], hv); fma4(az1, w3[k], hv);
            fma4(an0, w4[k], hv); fma4(an1, w5[k], hv);
        }
        if (kq) {
            f32x4* rp = &red[kq - 1][b4][0];
            rp[0] = f32x4{ar0.x, ar0.y, ar0.z, ar0.w};
            rp[1] = f32x4{ar1.x, ar1.y, ar1.z, ar1.w};
            rp[2] = f32x4{az0.x, az0.y, az0.z, az0.w};
            rp[3] = f32x4{az1.x, az1.y, az1.z, az1.w};
            rp[4] = f32x4{an0.x, an0.y, an0.z, an0.w};
            rp[5] = f32x4{an1.x, an1.y, an1.z, an1.w};
        }
        __syncthreads();
        if (kq == 0) {
#pragma unroll
            for (int p = 0; p < 7; ++p) {
                const f32x4* rp = &red[p][b4][0];
                f32x4 v;
                v = rp[0]; ar0.x += v[0]; ar0.y += v[1]; ar0.z += v[2]; ar0.w += v[3];
                v = rp[1]; ar1.x += v[0]; ar1.y += v[1]; ar1.z += v[2]; ar1.w += v[3];
                v = rp[2]; az0.x += v[0]; az0.y += v[1]; az0.z += v[2]; az0.w += v[3];
                v = rp[3]; az1.x += v[0]; az1.y += v[1]; az1.z += v[2]; az1.w += v[3];
                v = rp[4]; an0.x += v[0]; an0.y += v[1]; an0.z += v[2]; an0.w += v[3];
                v = rp[5]; an1.x += v[0]; an1.y += v[1]; an1.z += v[2]; an1.w += v[3];
            }
            const float4* xi4 = (const float4*)xiT;
            const float4* h4 = (const float4*)hTprev;
            float4 xr0 = xi4[(size_t)(j0)*64 + b4],          xr1 = xi4[(size_t)(j0 + 1) * 64 + b4];
            float4 xz0 = xi4[(size_t)(512 + j0) * 64 + b4],  xz1 = xi4[(size_t)(513 + j0) * 64 + b4];
            float4 xn0 = xi4[(size_t)(1024 + j0) * 64 + b4], xn1 = xi4[(size_t)(1025 + j0) * 64 + b4];
            float4 hv0 = h4[(size_t)j0 * 64 + b4],           hv1 = h4[(size_t)(j0 + 1) * 64 + b4];
            float br0 = bhh0[j0], br1 = bhh0[j0 + 1];
            float bz0 = bhh0[512 + j0], bz1 = bhh0[513 + j0];
            float bn0 = bhh0[1024 + j0], bn1 = bhh0[1025 + j0];
            float4 o0, o1;
            {
                float rr, zz, nn;
                rr = sigm(xr0.x + ar0.x + br0); zz = sigm(xz0.x + az0.x + bz0);
                nn = tanhf(xn0.x + rr * (an0.x + bn0)); o0.x = (1.f - zz) * nn + zz * hv0.x;
                rr = sigm(xr0.y + ar0.y + br0); zz = sigm(xz0.y + az0.y + bz0);
                nn = tanhf(xn0.y + rr * (an0.y + bn0)); o0.y = (1.f - zz) * nn + zz * hv0.y;
                rr = sigm(xr0.z + ar0.z + br0); zz = sigm(xz0.z + az0.z + bz0);
                nn = tanhf(xn0.z + rr * (an0.z + bn0)); o0.z = (1.f - zz) * nn + zz * hv0.z;
                rr = sigm(xr0.w + ar0.w + br0); zz = sigm(xz0.w + az0.w + bz0);
                nn = tanhf(xn0.w + rr * (an0.w + bn0)); o0.w = (1.f - zz) * nn + zz * hv0.w;
                rr = sigm(xr1.x + ar1.x + br1); zz = sigm(xz1.x + az1.x + bz1);
                nn = tanhf(xn1.x + rr * (an1.x + bn1)); o1.x = (1.f - zz) * nn + zz * hv1.x;
                rr = sigm(xr1.y + ar1.y + br1); zz = sigm(xz1.y + az1.y + bz1);
                nn = tanhf(xn1.y + rr * (an1.y + bn1)); o1.y = (1.f - zz) * nn + zz * hv1.y;
                rr = sigm(xr1.z + ar1.z + br1); zz = sigm(xz1.z + az1.z + bz1);
                nn = tanhf(xn1.z + rr * (an1.z + bn1)); o1.z = (1.f - zz) * nn + zz * hv1.z;
                rr = sigm(xr1.w + ar1.w + br1); zz = sigm(xz1.w + az1.w + bz1);
                nn = tanhf(xn1.w + rr * (an1.w + bn1)); o1.w = (1.f - zz) * nn + zz * hv1.w;
            }
            ((float4*)hTnext)[(size_t)j0 * 64 + b4] = o0;
            ((float4*)hTnext)[(size_t)(j0 + 1) * 64 + b4] = o1;
        }
    } else {
        // -------- rec1-fused: layer-1 step u = s-1 (gh1 + xi1 in one pass) --------
        int u = s - 1;
        if (u < 0) return;
        const float* h1prev = h1f + (size_t)((u - 1) & 1) * SLAB;
        const float* h0cur  = h0f + (size_t)(u & 1) * SLAB;
        float* h1next = h1f + (size_t)(u & 1) * SLAB;
        const int j0 = (blockIdx.x - 256) * 2;
        const float* g_0 = Whh1 + (size_t)(j0)*512 + kq * 64;
        const float* g_1 = Whh1 + (size_t)(j0 + 1) * 512 + kq * 64;
        const float* g_2 = Whh1 + (size_t)(512 + j0) * 512 + kq * 64;
        const float* g_3 = Whh1 + (size_t)(513 + j0) * 512 + kq * 64;
        const float* g_4 = Whh1 + (size_t)(1024 + j0) * 512 + kq * 64;
        const float* g_5 = Whh1 + (size_t)(1025 + j0) * 512 + kq * 64;
        const float* i_0 = Wih1 + (size_t)(j0)*512 + kq * 64;
        const float* i_1 = Wih1 + (size_t)(j0 + 1) * 512 + kq * 64;
        const float* i_2 = Wih1 + (size_t)(512 + j0) * 512 + kq * 64;
        const float* i_3 = Wih1 + (size_t)(513 + j0) * 512 + kq * 64;
        const float* i_4 = Wih1 + (size_t)(1024 + j0) * 512 + kq * 64;
        const float* i_5 = Wih1 + (size_t)(1025 + j0) * 512 + kq * 64;
        const float4* h1p = (const float4*)h1prev + (size_t)kq * 64 * 64 + b4;
        const float4* h0p = (const float4*)h0cur + (size_t)kq * 64 * 64 + b4;

        float4 gR0 = {0, 0, 0, 0}, gR1 = gR0, gZ0 = gR0, gZ1 = gR0, gN0 = gR0, gN1 = gR0;
        float4 xR0 = gR0, xR1 = gR0, xZ0 = gR0, xZ1 = gR0, xN0 = gR0, xN1 = gR0;
#pragma unroll 4
        for (int k = 0; k < 64; ++k) {
            float4 hv = h1p[(size_t)k * 64];
            float4 gv = h0p[(size_t)k * 64];
            fma4(gR0, g_0[k], hv); fma4(gR1, g_1[k], hv);
            fma4(gZ0, g_2[k], hv); fma4(gZ1, g_3[k], hv);
            fma4(gN0, g_4[k], hv); fma4(gN1, g_5[k], hv);
            fma4(xR0, i_0[k], gv); fma4(xR1, i_1[k], gv);
            fma4(xZ0, i_2[k], gv); fma4(xZ1, i_3[k], gv);
            fma4(xN0, i_4[k], gv); fma4(xN1, i_5[k], gv);
        }
        // two-pass reduction through the shared red buffer
        if (kq) {
            f32x4* rp = &red[kq - 1][b4][0];
            rp[0] = f32x4{gR0.x, gR0.y, gR0.z, gR0.w};
            rp[1] = f32x4{gR1.x, gR1.y, gR1.z, gR1.w};
            rp[2] = f32x4{gZ0.x, gZ0.y, gZ0.z, gZ0.w};
            rp[3] = f32x4{gZ1.x, gZ1.y, gZ1.z, gZ1.w};
            rp[4] = f32x4{gN0.x, gN0.y, gN0.z, gN0.w};
            rp[5] = f32x4{gN1.x, gN1.y, gN1.z, gN1.w};
        }
        __syncthreads();
        if (kq == 0) {
#pragma unroll
            for (int p = 0; p < 7; ++p) {
                const f32x4* rp = &red[p][b4][0];
                f32x4 v;
                v = rp[0]; gR0.x += v[0]; gR0.y += v[1]; gR0.z += v[2]; gR0.w += v[3];
                v = rp[1]; gR1.x += v[0]; gR1.y += v[1]; gR1.z += v[2]; gR1.w += v[3];
                v = rp[2]; gZ0.x += v[0]; gZ0.y += v[1]; gZ0.z += v[2]; gZ0.w += v[3];
                v = rp[3]; gZ1.x += v[0]; gZ1.y += v[1]; gZ1.z += v[2]; gZ1.w += v[3];
                v = rp[4]; gN0.x += v[0]; gN0.y += v[1]; gN0.z += v[2]; gN0.w += v[3];
                v = rp[5]; gN1.x += v[0]; gN1.y += v[1]; gN1.z += v[2]; gN1.w += v[3];
            }
        }
        __syncthreads();
        if (kq) {
            f32x4* rp = &red[kq - 1][b4][0];
            rp[0] = f32x4{xR0.x, xR0.y, xR0.z, xR0.w};
            rp[1] = f32x4{xR1.x, xR1.y, xR1.z, xR1.w};
            rp[2] = f32x4{xZ0.x, xZ0.y, xZ0.z, xZ0.w};
            rp[3] = f32x4{xZ1.x, xZ1.y, xZ1.z, xZ1.w};
            rp[4] = f32x4{xN0.x, xN0.y, xN0.z, xN0.w};
            rp[5] = f32x4{xN1.x, xN1.y, xN1.z, xN1.w};
        }
        __syncthreads();
        if (kq == 0) {
#pragma unroll
            for (int p = 0; p < 7; ++p) {
                const f32x4* rp = &red[p][b4][0];
                f32x4 v;
                v = rp[0]; xR0.x += v[0]; xR0.y += v[1]; xR0.z += v[2]; xR0.w += v[3];
                v = rp[1]; xR1.x += v[0]; xR1.y += v[1]; xR1.z += v[2]; xR1.w += v[3];
                v = rp[2]; xZ0.x += v[0]; xZ0.y += v[1]; xZ0.z += v[2]; xZ0.w += v[3];
                v = rp[3]; xZ1.x += v[0]; xZ1.y += v[1]; xZ1.z += v[2]; xZ1.w += v[3];
                v = rp[4]; xN0.x += v[0]; xN0.y += v[1]; xN0.z += v[2]; xN0.w += v[3];
                v = rp[5]; xN1.x += v[0]; xN1.y += v[1]; xN1.z += v[2]; xN1.w += v[3];
            }
            const float4* h4 = (const float4*)h1prev;
            float4 hv0 = h4[(size_t)j0 * 64 + b4], hv1 = h4[(size_t)(j0 + 1) * 64 + b4];
            float bir0 = bih1[j0], bir1 = bih1[j0 + 1];
            float biz0 = bih1[512 + j0], biz1 = bih1[513 + j0];
            float bin0 = bih1[1024 + j0], bin1 = bih1[1025 + j0];
            float bhr0 = bhh1[j0], bhr1 = bhh1[j0 + 1];
            float bhz0 = bhh1[512 + j0], bhz1 = bhh1[513 + j0];
            float bhn0 = bhh1[1024 + j0], bhn1 = bhh1[1025 + j0];
            float4 o0, o1;
            {
                float rr, zz, nn;
                rr = sigm(xR0.x + bir0 + gR0.x + bhr0); zz = sigm(xZ0.x + biz0 + gZ0.x + bhz0);
                nn = tanhf(xN0.x + bin0 + rr * (gN0.x + bhn0)); o0.x = (1.f - zz) * nn + zz * hv0.x;
                rr = sigm(xR0.y + bir0 + gR0.y + bhr0); zz = sigm(xZ0.y + biz0 + gZ0.y + bhz0);
                nn = tanhf(xN0.y + bin0 + rr * (gN0.y + bhn0)); o0.y = (1.f - zz) * nn + zz * hv0.y;
                rr = sigm(xR0.z + bir0 + gR0.z + bhr0); zz = sigm(xZ0.z + biz0 + gZ0.z + bhz0);
                nn = tanhf(xN0.z + bin0 + rr * (gN0.z + bhn0)); o0.z = (1.f - zz) * nn + zz * hv0.z;
                rr = sigm(xR0.w + bir0 + gR0.w + bhr0); zz = sigm(xZ0.w + biz0 + gZ0.w + bhz0);
                nn = tanhf(xN0.w + bin0 + rr * (gN0.w + bhn0)); o0.w = (1.f - zz) * nn + zz * hv0.w;
                rr = sigm(xR1.x + bir1 + gR1.x + bhr1); zz = sigm(xZ1.x + biz1 + gZ1.x + bhz1);
                nn = tanhf(xN1.x + bin1 + rr * (gN1.x + bhn1)); o1.x = (1.f - zz) * nn + zz * hv1.x;
                rr = sigm(xR1.y + bir1 + gR1.y + bhr1); zz = sigm(xZ1.y + biz1 + gZ1.y + bhz1);
                nn = tanhf(xN1.y + bin1 + rr * (gN1.y + bhn1)); o1.y = (1.f - zz) * nn + zz * hv1.y;
                rr = sigm(xR1.z + bir1 + gR1.z + bhr1); zz = sigm(xZ1.z + biz1 + gZ1.z + bhz1);
                nn = tanhf(xN1.z + bin1 + rr * (gN1.z + bhn1)); o1.z = (1.f - zz) * nn + zz * hv1.z;
                rr = sigm(xR1.w + bir1 + gR1.w + bhr1); zz = sigm(xZ1.w + biz1 + gZ1.w + bhz1);
                nn = tanhf(xN1.w + bin1 + rr * (gN1.w + bhn1)); o1.w = (1.f - zz) * nn + zz * hv1.w;
            }
            ((float4*)h1next)[(size_t)j0 * 64 + b4] = o0;
            ((float4*)h1next)[(size_t)(j0 + 1) * 64 + b4] = o1;
        }
    }
}

// hT[512][256] -> h[256][512]
__global__ __launch_bounds__(256) void hT_to_h(
    const float* __restrict__ hT, float* __restrict__ h) {
    __shared__ float tb[64][65];
    const int tid = threadIdx.x;
    const int k0 = blockIdx.x * 64, b0 = blockIdx.y * 64;
#pragma unroll
    for (int i = 0; i < 4; ++i) {
        int r = (tid >> 4) + 16 * i;
        int c = (tid & 15) * 4;
        float4 v = *(const float4*)(hT + (size_t)(k0 + r) * 256 + b0 + c);
        tb[c + 0][r] = v.x; tb[c + 1][r] = v.y; tb[c + 2][r] = v.z; tb[c + 3][r] = v.w;
    }
    __syncthreads();
#pragma unroll
    for (int i = 0; i < 4; ++i) {
        int r = (tid >> 4) + 16 * i;
        int c = (tid & 15) * 4;
        float4 v;
        v.x = tb[r][c]; v.y = tb[r][c + 1]; v.z = tb[r][c + 2]; v.w = tb[r][c + 3];
        *(float4*)(h + (size_t)(b0 + r) * 512 + k0 + c) = v;
    }
}

__device__ __forceinline__ float blockReduceSum(float v, float* tmp) {
    __syncthreads();
#pragma unroll
    for (int o = 32; o; o >>= 1) v += __shfl_down(v, o);
    if ((threadIdx.x & 63) == 0) tmp[threadIdx.x >> 6] = v;
    __syncthreads();
    if (threadIdx.x == 0) tmp[4] = tmp[0] + tmp[1] + tmp[2] + tmp[3];
    __syncthreads();
    return tmp[4];
}

__device__ __forceinline__ float blockReduceMax(float v, float* tmp) {
    __syncthreads();
#pragma unroll
    for (int o = 32; o; o >>= 1) v = fmaxf(v, __shfl_down(v, o));
    if ((threadIdx.x & 63) == 0) tmp[threadIdx.x >> 6] = v;
    __syncthreads();
    if (threadIdx.x == 0) tmp[4] = fmaxf(fmaxf(tmp[0], tmp[1]), fmaxf(tmp[2], tmp[3]));
    __syncthreads();
    return tmp[4];
}

__global__ __launch_bounds__(256) void head_kernel(
    const float* __restrict__ h1, const float* __restrict__ fcw,
    const float* __restrict__ fcb, float* __restrict__ out) {
    __shared__ __align__(16) float hrow[512];
    __shared__ float wv[512];
    __shared__ float ov[512];
    __shared__ float tmp[8];
    const int b = blockIdx.x, tid = threadIdx.x;
    hrow[tid]       = h1[(size_t)b * 512 + tid];
    hrow[tid + 256] = h1[(size_t)b * 512 + 256 + tid];
    __syncthreads();

    float s[2];
#pragma unroll
    for (int q = 0; q < 2; ++q) {
        int n = tid + q * 256;
        const float* wr = fcw + (size_t)n * 512;
        float acc = 0.f;
        for (int k = 0; k < 512; k += 4) {
            float4 wq = *(const float4*)(wr + k);
            acc += wq.x * hrow[k] + wq.y * hrow[k + 1] + wq.z * hrow[k + 2] + wq.w * hrow[k + 3];
        }
        float l = acc + fcb[n];
        s[q] = l / (1.f + expf(-l));
    }

    float mx = blockReduceMax(fmaxf(s[0], s[1]), tmp);
    float e0 = expf(s[0] - mx), e1 = expf(s[1] - mx);
    float sum = blockReduceSum(e0 + e1, tmp);
    float w0 = e0 / sum, w1 = e1 / sum;

    ov[tid] = w0;       ov[tid + 256] = w1;
    wv[tid]       = fminf(fmaxf(w0, 0.f), 0.1f);
    wv[tid + 256] = fminf(fmaxf(w1, 0.f), 0.1f);
    __syncthreads();

    for (int it = 0; it < 32; ++it) {
        float wc0 = wv[tid], wc1 = wv[tid + 256];
        float o0 = ov[tid], o1 = ov[tid + 256];
        float leftover = blockReduceSum((o0 - wc0) + (o1 - wc1), tmp);
        float n0 = (wc0 != 0.1f) ? wc0 : 0.f;
        float n1 = (wc1 != 0.1f) ? wc1 : 0.f;
        float denom = blockReduceSum(n0 + n1, tmp);
        float w20 = wc0 + leftover * n0 / denom;
        float w21 = wc1 + leftover * n1 / denom;
        float fl = ((w20 > 0.1f) || (w21 > 0.1f)) ? 1.f : 0.f;
        bool again = blockReduceSum(fl, tmp) > 0.f;
        __syncthreads();
        ov[tid] = w20; ov[tid + 256] = w21;
        wv[tid]       = again ? fminf(fmaxf(w20, 0.f), 0.1f) : w20;
        wv[tid + 256] = again ? fminf(fmaxf(w21, 0.f), 0.1f) : w21;
        __syncthreads();
        if (!again) break;
    }

    out[(size_t)b * 512 + tid]       = wv[tid];
    out[(size_t)b * 512 + 256 + tid] = wv[tid + 256];
}

extern "C" void kernel_launch(void* const* d_in, const int* in_sizes, int n_in,
                              void* d_out, int out_size, void* d_ws, size_t ws_size,
                              hipStream_t stream) {
    const float* x    = (const float*)d_in[0];
    const float* Wih0 = (const float*)d_in[1];
    const float* Whh0 = (const float*)d_in[2];
    const float* bih0 = (const float*)d_in[3];
    const float* bhh0 = (const float*)d_in[4];
    const float* Wih1 = (const float*)d_in[5];
    const float* Whh1 = (const float*)d_in[6];
    const float* bih1 = (const float*)d_in[7];
    const float* bhh1 = (const float*)d_in[8];
    const float* fcw  = (const float*)d_in[9];
    const float* fcb  = (const float*)d_in[10];
    float* out = (float*)d_out;

    const size_t WHALF = (size_t)G3 * HH;      // 786432
    unsigned short* W0ih_h = (unsigned short*)d_ws;
    unsigned short* W0ih_l = W0ih_h + WHALF;
    float* xi0 = (float*)(W0ih_l + WHALF);     // [CH][1536][256] fp32
    float* h0f = xi0 + (size_t)CH * XSLAB;     // [2][512][256]
    float* h1f = h0f + 2 * (size_t)SLAB;       // [2][512][256]
    float* h1n = h1f + 2 * (size_t)SLAB;       // [256][512]

    convert_split<<<(G3 * HH) / 1024, 256, 0, stream>>>(Wih0, W0ih_h, W0ih_l, G3 * HH);
    zero_kernel<<<SLAB / 256, 256, 0, stream>>>(h0f + SLAB, SLAB);
    zero_kernel<<<SLAB / 256, 256, 0, stream>>>(h1f + SLAB, SLAB);

    for (int c = 0; c < TT / CH; ++c) {
        xi_mfma_x<<<dim3(CH * 2, 12), 256, 0, stream>>>(W0ih_h, W0ih_l, x, c * CH,
                                                        bih0, xi0);
        for (int tl = 0; tl < CH; ++tl) {
            int s = c * CH + tl;
            fused_step<<<512, 512, 0, stream>>>(s, xi0 + (size_t)tl * XSLAB,
                                                Whh0, bhh0, Wih1, Whh1, bih1, bhh1,
                                                h0f, h1f);
        }
    }
    // final launch: only rec1-fused(t=127) active
    fused_step<<<512, 512, 0, stream>>>(128, xi0, Whh0, bhh0, Wih1, Whh1, bih1, bhh1,
                                        h0f, h1f);

    hT_to_h<<<dim3(8, 4), 256, 0, stream>>>(h1f + SLAB, h1n);
    head_kernel<<<BB, 256, 0, stream>>>(h1n, fcw, fcb, out);
}

// Round 8
// 2099.782 us; speedup vs baseline: 8.5094x; 1.6660x over previous
//
#include <hip/hip_runtime.h>
#include <math.h>

#define BB 256
#define TT 128
#define NN 512
#define HH 512
#define G3 1536
#define SLAB (HH * BB)     // 131072 elems
#define XSLAB (G3 * BB)    // 393216 floats
#define CH 16              // timesteps per xi0 chunk

typedef __attribute__((ext_vector_type(8))) short bf16x8;
typedef __attribute__((ext_vector_type(4))) float f32x4;

__device__ __forceinline__ unsigned short bf16_rne(float f) {
    union { float f; unsigned int u; } v; v.f = f;
    unsigned int r = (v.u + 0x7fffu + ((v.u >> 16) & 1u)) >> 16;
    return (unsigned short)r;
}
__device__ __forceinline__ float bf16_tof(unsigned short h) {
    union { float f; unsigned int u; } v; v.u = ((unsigned int)h) << 16;
    return v.f;
}
__device__ __forceinline__ float sigm(float v) { return 1.f / (1.f + expf(-v)); }

__global__ void zero_kernel(float* p, int n) {
    int i = blockIdx.x * blockDim.x + threadIdx.x;
    if (i < n) p[i] = 0.f;
}

// fp32 -> hi/lo bf16 split (row-major, for xi_mfma_x's W0ih)
__global__ __launch_bounds__(256) void convert_split(
    const float* __restrict__ in, unsigned short* __restrict__ hi,
    unsigned short* __restrict__ lo, int n) {
    int i = (blockIdx.x * 256 + threadIdx.x) * 4;
    if (i >= n) return;
    float4 v = *(const float4*)(in + i);
    float f[4] = {v.x, v.y, v.z, v.w};
    ushort4 h, l;
    unsigned short* hp = (unsigned short*)&h;
    unsigned short* lp = (unsigned short*)&l;
#pragma unroll
    for (int q = 0; q < 4; ++q) {
        unsigned short hh = bf16_rne(f[q]);
        hp[q] = hh;
        lp[q] = bf16_rne(f[q] - bf16_tof(hh));
    }
    *(ushort4*)(hi + i) = h;
    *(ushort4*)(lo + i) = l;
}

// One-time: pack Whh0/Wih1/Whh1 into split-bf16 staged tiles.
// tile (set,p,kc): [hi 48rows x 40k | lo 48x40 | pad] = 4096 ushorts (8192 B).
// rows = 3 gates x 16 j (j = p*16 + row&15, gate = row>>4).
__global__ __launch_bounds__(128) void pack_rec(
    const float* __restrict__ Whh0, const float* __restrict__ Wih1,
    const float* __restrict__ Whh1, unsigned short* __restrict__ pk) {
    int bi = blockIdx.x;                 // 0..1535 = set*512 + p*16 + kc
    int set = bi >> 9, rem = bi & 511;
    int p = rem >> 4, kc = rem & 15;
    const float* W = (set == 0) ? Whh0 : (set == 1) ? Wih1 : Whh1;
    unsigned short* tp = pk + (size_t)bi * 4096;
    int tid = threadIdx.x;
#pragma unroll
    for (int i = 0; i < 12; ++i) {
        int idx = tid * 12 + i;          // 0..1535
        int row = idx >> 5, k = idx & 31;
        int grow = (row >> 4) * 512 + p * 16 + (row & 15);
        float v = W[(size_t)grow * 512 + kc * 32 + k];
        unsigned short h = bf16_rne(v);
        tp[row * 40 + k] = h;
        tp[1920 + row * 40 + k] = bf16_rne(v - bf16_tof(h));
    }
    if (tid < 32)
#pragma unroll
        for (int i = 0; i < 8; ++i) tp[3840 + tid * 8 + i] = 0;
}

// xi0 chunk GEMM (r7, proven): out[tl][g][b] = W0ih x x[:, t0+tl, :] + bih0
__global__ __launch_bounds__(256) void xi_mfma_x(
    const unsigned short* __restrict__ Wh, const unsigned short* __restrict__ Wl,
    const float* __restrict__ x, int t0,
    const float* __restrict__ bias, float* __restrict__ out) {
    __shared__ unsigned short As[2][128][40];
    __shared__ unsigned short Bs[2][128][40];
    const int tid = threadIdx.x;
    const int n0 = blockIdx.x * 128;
    const int g0 = blockIdx.y * 128;
    const int tl = n0 >> 8, b0 = n0 & 255;
    const int tg = t0 + tl;
    const int w = tid >> 6, lane = tid & 63;
    const int wg = (w >> 1) * 64, wb = (w & 1) * 64;
    const int l15 = lane & 15, l4 = lane >> 4;
    const int sr = tid >> 2, sc = (tid & 3) * 8;

    f32x4 acc[4][4] = {};
    for (int kc = 0; kc < 512; kc += 32) {
        uint4 a0 = *(const uint4*)(Wh + (size_t)(g0 + sr) * 512 + kc + sc);
        uint4 a1 = *(const uint4*)(Wh + (size_t)(g0 + 64 + sr) * 512 + kc + sc);
        uint4 a2 = *(const uint4*)(Wl + (size_t)(g0 + sr) * 512 + kc + sc);
        uint4 a3 = *(const uint4*)(Wl + (size_t)(g0 + 64 + sr) * 512 + kc + sc);
        const float* xr0 = x + ((size_t)(b0 + sr) * TT + tg) * NN + kc + sc;
        const float* xr1 = x + ((size_t)(b0 + 64 + sr) * TT + tg) * NN + kc + sc;
        float4 f00 = *(const float4*)xr0, f01 = *(const float4*)(xr0 + 4);
        float4 f10 = *(const float4*)xr1, f11 = *(const float4*)(xr1 + 4);
        float fa[8] = {f00.x, f00.y, f00.z, f00.w, f01.x, f01.y, f01.z, f01.w};
        float fb[8] = {f10.x, f10.y, f10.z, f10.w, f11.x, f11.y, f11.z, f11.w};
        unsigned short h0v[8], l0v[8], h1v[8], l1v[8];
#pragma unroll
        for (int q = 0; q < 8; ++q) {
            unsigned short hh = bf16_rne(fa[q]);
            h0v[q] = hh; l0v[q] = bf16_rne(fa[q] - bf16_tof(hh));
            hh = bf16_rne(fb[q]);
            h1v[q] = hh; l1v[q] = bf16_rne(fb[q] - bf16_tof(hh));
        }
        __syncthreads();
        *(uint4*)&As[0][sr][sc] = a0;      *(uint4*)&As[0][64 + sr][sc] = a1;
        *(uint4*)&As[1][sr][sc] = a2;      *(uint4*)&As[1][64 + sr][sc] = a3;
        *(uint4*)&Bs[0][sr][sc] = *(uint4*)h0v;  *(uint4*)&Bs[0][64 + sr][sc] = *(uint4*)h1v;
        *(uint4*)&Bs[1][sr][sc] = *(uint4*)l0v;  *(uint4*)&Bs[1][64 + sr][sc] = *(uint4*)l1v;
        __syncthreads();
        bf16x8 ah[4], al[4], bh[4], bl[4];
#pragma unroll
        for (int i = 0; i < 4; ++i) {
            ah[i] = *(const bf16x8*)&As[0][wg + 16 * i + l15][l4 * 8];
            al[i] = *(const bf16x8*)&As[1][wg + 16 * i + l15][l4 * 8];
            bh[i] = *(const bf16x8*)&Bs[0][wb + 16 * i + l15][l4 * 8];
            bl[i] = *(const bf16x8*)&Bs[1][wb + 16 * i + l15][l4 * 8];
        }
#pragma unroll
        for (int i = 0; i < 4; ++i)
#pragma unroll
            for (int j = 0; j < 4; ++j) {
                acc[i][j] = __builtin_amdgcn_mfma_f32_16x16x32_bf16(ah[i], bh[j], acc[i][j], 0, 0, 0);
                acc[i][j] = __builtin_amdgcn_mfma_f32_16x16x32_bf16(ah[i], bl[j], acc[i][j], 0, 0, 0);
                acc[i][j] = __builtin_amdgcn_mfma_f32_16x16x32_bf16(al[i], bh[j], acc[i][j], 0, 0, 0);
            }
    }
    float* op = out + (size_t)tl * XSLAB;
#pragma unroll
    for (int i = 0; i < 4; ++i) {
        int gbase = g0 + wg + 16 * i + l4 * 4;
#pragma unroll
        for (int r = 0; r < 4; ++r) {
            float bv = bias[gbase + r];
#pragma unroll
            for (int j = 0; j < 4; ++j)
                op[(size_t)(gbase + r) * 256 + b0 + wb + 16 * j + l15] = acc[i][j][r] + bv;
        }
    }
}

// Per-step kernel: 3 sections x 256 blocks.
//  sec0 L0(t=s):  gh0 = Whh0 x h0[t-1]bf, gates -> h0[t] (+ bf16 b-major)
//  sec1 XI1(t=s-1): xi1 = Wih1 x h0[t]bf + bih1 -> xi1 slab
//  sec2 L1(t=s-2): gh1 = Whh1 x h1[t-1]bf, gates(xi1) -> h1[t] (+ bf16)
// block: 48rows x 32b tile; 4 waves = 2 bcol x 2 k-groups; reg-staged dbuf LDS.
__global__ __launch_bounds__(256) void step_mfma(
    int s, const unsigned short* __restrict__ pk,
    const float* __restrict__ xi0, float* __restrict__ xi1,
    const float* __restrict__ bih1,
    const float* __restrict__ bhh0, const float* __restrict__ bhh1,
    float* __restrict__ h0f, float* __restrict__ h1f,
    unsigned short* __restrict__ H0h, unsigned short* __restrict__ H0l,
    unsigned short* __restrict__ H1h, unsigned short* __restrict__ H1l) {
    __shared__ __align__(16) unsigned short lds[16384];  // 4 bufs x 4096 ushorts
    __shared__ float hs[16][33];
    const int bi = blockIdx.x;
    const int sec = bi >> 8;
    const int local = bi & 255;
    const int t = (sec == 0) ? s : (sec == 1) ? s - 1 : s - 2;
    if (t < 0 || t > 127) return;
    const int p = (local & 7) * 4 + ((local >> 3) & 3);   // XCD-grouped panels
    const int bt = local >> 5;
    const int b0 = bt * 32;
    const int tid = threadIdx.x, w = tid >> 6, lane = tid & 63;
    const int l15 = lane & 15, l4 = lane >> 4;
    const int kk = w >> 1, bcol = w & 1;
    const int lt = tid & 127;

    const unsigned short *Bh, *Bl;
    if (sec == 0) { int sl = (t - 1) & 1; Bh = H0h + (size_t)sl * SLAB; Bl = H0l + (size_t)sl * SLAB; }
    else if (sec == 1) { int sl = t & 1; Bh = H0h + (size_t)sl * SLAB; Bl = H0l + (size_t)sl * SLAB; }
    else { int sl = (t - 1) & 1; Bh = H1h + (size_t)sl * SLAB; Bl = H1l + (size_t)sl * SLAB; }

    const unsigned short* Ab = pk + ((size_t)(sec * 32 + p) * 16) * 4096;
    const int brow = b0 + bcol * 16 + l15;
    const unsigned short* bhp = Bh + (size_t)brow * 512 + kk * 256 + l4 * 8;
    const unsigned short* blp = Bl + (size_t)brow * 512 + kk * 256 + l4 * 8;

    f32x4 cR = {0, 0, 0, 0}, cZ = cR, cN = cR;
    uint4 rg0, rg1, rg2, rg3;
    {   // prologue: tile kc = kk*8 -> regs -> buf0
        const uint4* g0p = (const uint4*)Ab + (size_t)(kk * 8) * 256 + lt;
        rg0 = g0p[0]; rg1 = g0p[128]; /* 256 uint4 per tile? no: */
        rg2 = g0p[0]; // placeholder fix below
    }
    // NOTE: tile = 4096 ushorts = 512 uint4; rounds of 128.
    {
        const uint4* g0p = (const uint4*)Ab + (size_t)(kk * 8) * 512 + lt;
        rg0 = g0p[0]; rg1 = g0p[128]; rg2 = g0p[256]; rg3 = g0p[384];
        uint4* lp = (uint4*)lds + (kk * 2 + 0) * 512 + lt;
        lp[0] = rg0; lp[128] = rg1; lp[256] = rg2; lp[384] = rg3;
    }
    __syncthreads();
#pragma unroll
    for (int i = 0; i < 8; ++i) {
        const int d = i & 1;
        if (i < 7) {
            const uint4* gn = (const uint4*)Ab + (size_t)(kk * 8 + i + 1) * 512 + lt;
            rg0 = gn[0]; rg1 = gn[128]; rg2 = gn[256]; rg3 = gn[384];
        }
        const unsigned short* tb = lds + (kk * 2 + d) * 4096;
        bf16x8 aRh = *(const bf16x8*)(tb + (l15) * 40 + l4 * 8);
        bf16x8 aRl = *(const bf16x8*)(tb + 1920 + (l15) * 40 + l4 * 8);
        bf16x8 aZh = *(const bf16x8*)(tb + (16 + l15) * 40 + l4 * 8);
        bf16x8 aZl = *(const bf16x8*)(tb + 1920 + (16 + l15) * 40 + l4 * 8);
        bf16x8 aNh = *(const bf16x8*)(tb + (32 + l15) * 40 + l4 * 8);
        bf16x8 aNl = *(const bf16x8*)(tb + 1920 + (32 + l15) * 40 + l4 * 8);
        bf16x8 bh = *(const bf16x8*)(bhp + i * 32);
        bf16x8 bl = *(const bf16x8*)(blp + i * 32);
        cR = __builtin_amdgcn_mfma_f32_16x16x32_bf16(aRh, bh, cR, 0, 0, 0);
        cR = __builtin_amdgcn_mfma_f32_16x16x32_bf16(aRh, bl, cR, 0, 0, 0);
        cR = __builtin_amdgcn_mfma_f32_16x16x32_bf16(aRl, bh, cR, 0, 0, 0);
        cZ = __builtin_amdgcn_mfma_f32_16x16x32_bf16(aZh, bh, cZ, 0, 0, 0);
        cZ = __builtin_amdgcn_mfma_f32_16x16x32_bf16(aZh, bl, cZ, 0, 0, 0);
        cZ = __builtin_amdgcn_mfma_f32_16x16x32_bf16(aZl, bh, cZ, 0, 0, 0);
        cN = __builtin_amdgcn_mfma_f32_16x16x32_bf16(aNh, bh, cN, 0, 0, 0);
        cN = __builtin_amdgcn_mfma_f32_16x16x32_bf16(aNh, bl, cN, 0, 0, 0);
        cN = __builtin_amdgcn_mfma_f32_16x16x32_bf16(aNl, bh, cN, 0, 0, 0);
        if (i < 7) {
            uint4* lp = (uint4*)lds + (kk * 2 + (d ^ 1)) * 512 + lt;
            lp[0] = rg0; lp[128] = rg1; lp[256] = rg2; lp[384] = rg3;
        }
        __syncthreads();
    }
    // cross-k-group reduce (reuse lds)
    float* red = (float*)lds;
    if (kk == 1) {
        int o = (bcol * 64 + lane) * 12;
        *(f32x4*)(red + o) = cR; *(f32x4*)(red + o + 4) = cZ; *(f32x4*)(red + o + 8) = cN;
    }
    __syncthreads();
    if (kk == 0) {
        int o = (bcol * 64 + lane) * 12;
        f32x4 u;
        u = *(f32x4*)(red + o);     cR += u;
        u = *(f32x4*)(red + o + 4); cZ += u;
        u = *(f32x4*)(red + o + 8); cN += u;
        const int b = b0 + bcol * 16 + l15;
        if (sec == 1) {
            float* xo = xi1 + (size_t)(t & 1) * XSLAB;
#pragma unroll
            for (int q = 0; q < 4; ++q) {
                int jrow = p * 16 + l4 * 4 + q;
                xo[(size_t)jrow * 256 + b]          = cR[q] + bih1[jrow];
                xo[(size_t)(512 + jrow) * 256 + b]  = cZ[q] + bih1[512 + jrow];
                xo[(size_t)(1024 + jrow) * 256 + b] = cN[q] + bih1[1024 + jrow];
            }
        } else {
            const float *xi, *bhh, *hpv;
            float* hnew;
            if (sec == 0) {
                xi = xi0 + (size_t)(t & (CH - 1)) * XSLAB;
                bhh = bhh0;
                hpv = h0f + (size_t)((t - 1) & 1) * SLAB;
                hnew = h0f + (size_t)(t & 1) * SLAB;
            } else {
                xi = xi1 + (size_t)(t & 1) * XSLAB;
                bhh = bhh1;
                hpv = h1f + (size_t)((t - 1) & 1) * SLAB;
                hnew = h1f + (size_t)(t & 1) * SLAB;
            }
#pragma unroll
            for (int q = 0; q < 4; ++q) {
                int jl = l4 * 4 + q;
                int jrow = p * 16 + jl;
                float xr = xi[(size_t)jrow * 256 + b];
                float xz = xi[(size_t)(512 + jrow) * 256 + b];
                float xn = xi[(size_t)(1024 + jrow) * 256 + b];
                float hp = hpv[(size_t)jrow * 256 + b];
                float rr = sigm(xr + cR[q] + bhh[jrow]);
                float zz = sigm(xz + cZ[q] + bhh[512 + jrow]);
                float nn = tanhf(xn + rr * (cN[q] + bhh[1024 + jrow]));
                float hv = (1.f - zz) * nn + zz * hp;
                hnew[(size_t)jrow * 256 + b] = hv;
                hs[jl][bcol * 16 + l15] = hv;
            }
        }
    }
    if (sec != 1) {
        __syncthreads();
        if (tid < 128) {
            int blocal = tid >> 2, j4 = (tid & 3) * 4;
            unsigned short hq[4], lq[4];
#pragma unroll
            for (int i2 = 0; i2 < 4; ++i2) {
                float v = hs[j4 + i2][blocal];
                unsigned short hh = bf16_rne(v);
                hq[i2] = hh; lq[i2] = bf16_rne(v - bf16_tof(hh));
            }
            unsigned short *Hh, *Hl;
            if (sec == 0) { Hh = H0h + (size_t)(t & 1) * SLAB; Hl = H0l + (size_t)(t & 1) * SLAB; }
            else          { Hh = H1h + (size_t)(t & 1) * SLAB; Hl = H1l + (size_t)(t & 1) * SLAB; }
            size_t o = (size_t)(b0 + blocal) * 512 + p * 16 + j4;
            *(ushort4*)(Hh + o) = *(ushort4*)hq;
            *(ushort4*)(Hl + o) = *(ushort4*)lq;
        }
    }
}

// ---- tail -------------------------------------------------------------

__global__ __launch_bounds__(256) void hT_to_h(
    const float* __restrict__ hT, float* __restrict__ h) {
    __shared__ float tb[64][65];
    const int tid = threadIdx.x;
    const int k0 = blockIdx.x * 64, b0 = blockIdx.y * 64;
#pragma unroll
    for (int i = 0; i < 4; ++i) {
        int r = (tid >> 4) + 16 * i;
        int c = (tid & 15) * 4;
        float4 v = *(const float4*)(hT + (size_t)(k0 + r) * 256 + b0 + c);
        tb[c + 0][r] = v.x; tb[c + 1][r] = v.y; tb[c + 2][r] = v.z; tb[c + 3][r] = v.w;
    }
    __syncthreads();
#pragma unroll
    for (int i = 0; i < 4; ++i) {
        int r = (tid >> 4) + 16 * i;
        int c = (tid & 15) * 4;
        float4 v;
        v.x = tb[r][c]; v.y = tb[r][c + 1]; v.z = tb[r][c + 2]; v.w = tb[r][c + 3];
        *(float4*)(h + (size_t)(b0 + r) * 512 + k0 + c) = v;
    }
}

__device__ __forceinline__ float blockReduceSum(float v, float* tmp) {
    __syncthreads();
#pragma unroll
    for (int o = 32; o; o >>= 1) v += __shfl_down(v, o);
    if ((threadIdx.x & 63) == 0) tmp[threadIdx.x >> 6] = v;
    __syncthreads();
    if (threadIdx.x == 0) tmp[4] = tmp[0] + tmp[1] + tmp[2] + tmp[3];
    __syncthreads();
    return tmp[4];
}

__device__ __forceinline__ float blockReduceMax(float v, float* tmp) {
    __syncthreads();
#pragma unroll
    for (int o = 32; o; o >>= 1) v = fmaxf(v, __shfl_down(v, o));
    if ((threadIdx.x & 63) == 0) tmp[threadIdx.x >> 6] = v;
    __syncthreads();
    if (threadIdx.x == 0) tmp[4] = fmaxf(fmaxf(tmp[0], tmp[1]), fmaxf(tmp[2], tmp[3]));
    __syncthreads();
    return tmp[4];
}

__global__ __launch_bounds__(256) void head_kernel(
    const float* __restrict__ h1, const float* __restrict__ fcw,
    const float* __restrict__ fcb, float* __restrict__ out) {
    __shared__ __align__(16) float hrow[512];
    __shared__ float wv[512];
    __shared__ float ov[512];
    __shared__ float tmp[8];
    const int b = blockIdx.x, tid = threadIdx.x;
    hrow[tid]       = h1[(size_t)b * 512 + tid];
    hrow[tid + 256] = h1[(size_t)b * 512 + 256 + tid];
    __syncthreads();

    float s[2];
#pragma unroll
    for (int q = 0; q < 2; ++q) {
        int n = tid + q * 256;
        const float* wr = fcw + (size_t)n * 512;
        float acc = 0.f;
        for (int k = 0; k < 512; k += 4) {
            float4 wq = *(const float4*)(wr + k);
            acc += wq.x * hrow[k] + wq.y * hrow[k + 1] + wq.z * hrow[k + 2] + wq.w * hrow[k + 3];
        }
        float l = acc + fcb[n];
        s[q] = l / (1.f + expf(-l));
    }

    float mx = blockReduceMax(fmaxf(s[0], s[1]), tmp);
    float e0 = expf(s[0] - mx), e1 = expf(s[1] - mx);
    float sum = blockReduceSum(e0 + e1, tmp);
    float w0 = e0 / sum, w1 = e1 / sum;

    ov[tid] = w0;       ov[tid + 256] = w1;
    wv[tid]       = fminf(fmaxf(w0, 0.f), 0.1f);
    wv[tid + 256] = fminf(fmaxf(w1, 0.f), 0.1f);
    __syncthreads();

    for (int it = 0; it < 32; ++it) {
        float wc0 = wv[tid], wc1 = wv[tid + 256];
        float o0 = ov[tid], o1 = ov[tid + 256];
        float leftover = blockReduceSum((o0 - wc0) + (o1 - wc1), tmp);
        float n0 = (wc0 != 0.1f) ? wc0 : 0.f;
        float n1 = (wc1 != 0.1f) ? wc1 : 0.f;
        float denom = blockReduceSum(n0 + n1, tmp);
        float w20 = wc0 + leftover * n0 / denom;
        float w21 = wc1 + leftover * n1 / denom;
        float fl = ((w20 > 0.1f) || (w21 > 0.1f)) ? 1.f : 0.f;
        bool again = blockReduceSum(fl, tmp) > 0.f;
        __syncthreads();
        ov[tid] = w20; ov[tid + 256] = w21;
        wv[tid]       = again ? fminf(fmaxf(w20, 0.f), 0.1f) : w20;
        wv[tid + 256] = again ? fminf(fmaxf(w21, 0.f), 0.1f) : w21;
        __syncthreads();
        if (!again) break;
    }

    out[(size_t)b * 512 + tid]       = wv[tid];
    out[(size_t)b * 512 + 256 + tid] = wv[tid + 256];
}

extern "C" void kernel_launch(void* const* d_in, const int* in_sizes, int n_in,
                              void* d_out, int out_size, void* d_ws, size_t ws_size,
                              hipStream_t stream) {
    const float* x    = (const float*)d_in[0];
    const float* Wih0 = (const float*)d_in[1];
    const float* Whh0 = (const float*)d_in[2];
    const float* bih0 = (const float*)d_in[3];
    const float* bhh0 = (const float*)d_in[4];
    const float* Wih1 = (const float*)d_in[5];
    const float* Whh1 = (const float*)d_in[6];
    const float* bih1 = (const float*)d_in[7];
    const float* bhh1 = (const float*)d_in[8];
    const float* fcw  = (const float*)d_in[9];
    const float* fcb  = (const float*)d_in[10];
    float* out = (float*)d_out;

    const size_t WHALF = (size_t)G3 * HH;            // 786432
    unsigned short* W0h = (unsigned short*)d_ws;
    unsigned short* W0l = W0h + WHALF;
    unsigned short* pk  = W0l + WHALF;               // 1536*4096 ushorts
    float* xi0 = (float*)(pk + (size_t)1536 * 4096); // [CH][XSLAB]
    float* xi1 = xi0 + (size_t)CH * XSLAB;           // [2][XSLAB]
    float* h0f = xi1 + 2 * (size_t)XSLAB;            // [2][SLAB]
    float* h1f = h0f + 2 * (size_t)SLAB;             // [2][SLAB]
    float* h1n = h1f + 2 * (size_t)SLAB;             // [SLAB]
    unsigned short* H0h = (unsigned short*)(h1n + SLAB);  // [2][SLAB] each
    unsigned short* H0l = H0h + 2 * (size_t)SLAB;
    unsigned short* H1h = H0l + 2 * (size_t)SLAB;
    unsigned short* H1l = H1h + 2 * (size_t)SLAB;

    convert_split<<<(G3 * HH) / 1024, 256, 0, stream>>>(Wih0, W0h, W0l, G3 * HH);
    pack_rec<<<1536, 128, 0, stream>>>(Whh0, Wih1, Whh1, pk);
    zero_kernel<<<SLAB / 256, 256, 0, stream>>>(h0f + SLAB, SLAB);
    zero_kernel<<<SLAB / 256, 256, 0, stream>>>(h1f + SLAB, SLAB);
    zero_kernel<<<(SLAB / 2) / 256, 256, 0, stream>>>((float*)(H0h + SLAB), SLAB / 2);
    zero_kernel<<<(SLAB / 2) / 256, 256, 0, stream>>>((float*)(H0l + SLAB), SLAB / 2);
    zero_kernel<<<(SLAB / 2) / 256, 256, 0, stream>>>((float*)(H1h + SLAB), SLAB / 2);
    zero_kernel<<<(SLAB / 2) / 256, 256, 0, stream>>>((float*)(H1l + SLAB), SLAB / 2);

    for (int c = 0; c < TT / CH; ++c) {
        xi_mfma_x<<<dim3(CH * 2, 12), 256, 0, stream>>>(W0h, W0l, x, c * CH, bih0, xi0);
        for (int tl = 0; tl < CH; ++tl) {
            int s = c * CH + tl;
            step_mfma<<<768, 256, 0, stream>>>(s, pk, xi0, xi1, bih1, bhh0, bhh1,
                                               h0f, h1f, H0h, H0l, H1h, H1l);
        }
    }
    step_mfma<<<768, 256, 0, stream>>>(128, pk, xi0, xi1, bih1, bhh0, bhh1,
                                       h0f, h1f, H0h, H0l, H1h, H1l);
    step_mfma<<<768, 256, 0, stream>>>(129, pk, xi0, xi1, bih1, bhh0, bhh1,
                                       h0f, h1f, H0h, H0l, H1h, H1l);

    hT_to_h<<<dim3(8, 4), 256, 0, stream>>>(h1f + SLAB, h1n);
    head_kernel<<<BB, 256, 0, stream>>>(h1n, fcw, fcb, out);
}